// Round 1
// baseline (817.903 us; speedup 1.0000x reference)
//
#include <hip/hip_runtime.h>
#include <hip/hip_bf16.h>
#include <cstdint>
#include <cstddef>

// ---------------------------------------------------------------------------
// L4maAttention: hidden(1,1024,4096) f32 -> out(1,1024,4096) f32
// H=32 q-heads, HKV=8 kv-heads (G=4), D=128, L=3072 kv (2048 cached + 1024 new)
// Precision plan: split-bf16 (hi+lo, 3-term) for Q/K projections and QK^T;
// plain bf16 for V, PV, O-proj. fp32 softmax.
// ---------------------------------------------------------------------------

typedef __bf16 bf16;
typedef __bf16 bf16x8 __attribute__((ext_vector_type(8)));
typedef __bf16 bf16x4 __attribute__((ext_vector_type(4)));
typedef float  f32x4  __attribute__((ext_vector_type(4)));

#define HIDN 4096
#define NHEAD 32
#define NKV 8
#define DHEAD 128
#define LCTX 3072
#define PASTN 2048
#define STOK 1024

__device__ __forceinline__ f32x4 mfma16(bf16x8 a, bf16x8 b, f32x4 c) {
    return __builtin_amdgcn_mfma_f32_16x16x32_bf16(a, b, c, 0, 0, 0);
}

__device__ __forceinline__ void split_bf(float x, bf16& h, bf16& l) {
    h = (bf16)x;
    l = (bf16)(x - (float)h);
}

// ---------------------------------------------------------------------------
// GEMM: C[M,N] = A[M,K] @ B[N,K]^T.  128x128 tile, BK=64, 4 waves (2x2 of 64x64).
// NTERMS==3: split-bf16 A and B (acc += Ah*Bh + Ah*Bl + Al*Bh).
// EPI==0: fused QKV epilogue (col<4096 -> qf32, <5120 -> kf32, else V->cv bf16)
// EPI==1: plain fp32 C.
// ABF16: A is already bf16 (O-proj path).
// ---------------------------------------------------------------------------
template <int NTERMS, int EPI, bool ABF16>
__global__ __launch_bounds__(256, 2) void gemm_bt(
    const void* __restrict__ Ap,
    const float* __restrict__ B0, const float* __restrict__ B1,
    const float* __restrict__ B2,
    float* __restrict__ Cf, float* __restrict__ Ck, bf16* __restrict__ Cv,
    int M, int N, int K)
{
    constexpr int BM = 128, BN = 128, BK = 64;
    __shared__ bf16 Ah[BM * BK];
    __shared__ bf16 Bh[BN * BK];
    __shared__ bf16 Al[NTERMS == 3 ? BM * BK : 8];
    __shared__ bf16 Bl[NTERMS == 3 ? BN * BK : 8];

    const int t = threadIdx.x;
    const int lane = t & 63, w = t >> 6, wm = w >> 1, wn = w & 1;
    const int l16 = lane & 15, g16 = lane >> 4;
    const int m0 = blockIdx.y * BM, n0 = blockIdx.x * BN;

    const float* Bbase = B0;
    int nb = n0;
    if (EPI == 0) {
        if (n0 >= 5120)      { Bbase = B2; nb = n0 - 5120; }
        else if (n0 >= 4096) { Bbase = B1; nb = n0 - 4096; }
    }

    f32x4 acc[4][4];
#pragma unroll
    for (int i = 0; i < 4; i++)
#pragma unroll
        for (int j = 0; j < 4; j++) acc[i][j] = (f32x4){0.f, 0.f, 0.f, 0.f};

    for (int k0 = 0; k0 < K; k0 += BK) {
        // ---- stage A ----
        if (!ABF16) {
            const float* As = (const float*)Ap;
#pragma unroll
            for (int i = 0; i < 8; i++) {
                int f = i * 256 + t;
                int row = f >> 4, c4 = f & 15;
                f32x4 v = *(const f32x4*)(As + (size_t)(m0 + row) * K + k0 + c4 * 4);
                bf16x4 hi, lo;
#pragma unroll
                for (int j = 0; j < 4; j++) { bf16 h, l; split_bf(v[j], h, l); hi[j] = h; lo[j] = l; }
                int base = row * 64 + (((c4 >> 1) ^ (row & 7)) << 3) + ((c4 & 1) << 2);
                *(bf16x4*)&Ah[base] = hi;
                if (NTERMS == 3) *(bf16x4*)&Al[base] = lo;
            }
        } else {
            const bf16* As = (const bf16*)Ap;
#pragma unroll
            for (int i = 0; i < 4; i++) {
                int u = i * 256 + t;
                int row = u >> 3, g = u & 7;
                bf16x8 v = *(const bf16x8*)(As + (size_t)(m0 + row) * K + k0 + g * 8);
                *(bf16x8*)&Ah[row * 64 + ((g ^ (row & 7)) << 3)] = v;
            }
        }
        // ---- stage B (always fp32 source) ----
        {
#pragma unroll
            for (int i = 0; i < 8; i++) {
                int f = i * 256 + t;
                int row = f >> 4, c4 = f & 15;
                f32x4 v = *(const f32x4*)(Bbase + (size_t)(nb + row) * K + k0 + c4 * 4);
                bf16x4 hi, lo;
#pragma unroll
                for (int j = 0; j < 4; j++) { bf16 h, l; split_bf(v[j], h, l); hi[j] = h; lo[j] = l; }
                int base = row * 64 + (((c4 >> 1) ^ (row & 7)) << 3) + ((c4 & 1) << 2);
                *(bf16x4*)&Bh[base] = hi;
                if (NTERMS == 3) *(bf16x4*)&Bl[base] = lo;
            }
        }
        __syncthreads();

        // ---- compute ----
#pragma unroll
        for (int ks = 0; ks < 2; ks++) {
            bf16x8 ah[4], al[4];
#pragma unroll
            for (int mi = 0; mi < 4; mi++) {
                int r = wm * 64 + mi * 16 + l16;
                int g = ks * 4 + g16;
                int la = r * 64 + ((g ^ (r & 7)) << 3);
                ah[mi] = *(bf16x8*)&Ah[la];
                if (NTERMS == 3) al[mi] = *(bf16x8*)&Al[la];
            }
#pragma unroll
            for (int ni = 0; ni < 4; ni++) {
                int r = wn * 64 + ni * 16 + l16;
                int g = ks * 4 + g16;
                int la = r * 64 + ((g ^ (r & 7)) << 3);
                bf16x8 bh = *(bf16x8*)&Bh[la];
                bf16x8 bl;
                if (NTERMS == 3) bl = *(bf16x8*)&Bl[la];
#pragma unroll
                for (int mi = 0; mi < 4; mi++) {
                    acc[mi][ni] = mfma16(ah[mi], bh, acc[mi][ni]);
                    if (NTERMS == 3) {
                        acc[mi][ni] = mfma16(ah[mi], bl, acc[mi][ni]);
                        acc[mi][ni] = mfma16(al[mi], bh, acc[mi][ni]);
                    }
                }
            }
        }
        __syncthreads();
    }

    // ---- epilogue ----
#pragma unroll
    for (int mi = 0; mi < 4; mi++)
#pragma unroll
        for (int ni = 0; ni < 4; ni++)
#pragma unroll
            for (int r = 0; r < 4; r++) {
                int row = m0 + wm * 64 + mi * 16 + (g16 << 2) + r;
                int col = n0 + wn * 64 + ni * 16 + l16;
                float val = acc[mi][ni][r];
                if (EPI == 0) {
                    if (col < 4096) {
                        Cf[(size_t)row * 4096 + col] = val;            // q fp32
                    } else if (col < 5120) {
                        Ck[(size_t)row * 1024 + (col - 4096)] = val;   // k fp32
                    } else {
                        int c = col - 5120;
                        int hh = c >> 7, d = c & 127;                  // v -> cv bf16 @ l=2048+row
                        Cv[((size_t)hh * LCTX + PASTN + row) * DHEAD + d] = (bf16)val;
                    }
                } else {
                    Cf[(size_t)row * N + col] = val;
                }
            }
}

// ---------------------------------------------------------------------------
// RoPE on q (fp32 in d_out scratch) -> q_hi/q_lo bf16, with 1/sqrt(D) folded in.
// ---------------------------------------------------------------------------
__global__ void rope_q_kernel(const float* __restrict__ qf,
                              const float* __restrict__ cosp,
                              const float* __restrict__ sinp,
                              bf16* __restrict__ qhi, bf16* __restrict__ qlo)
{
    int i4 = blockIdx.x * 256 + threadIdx.x;  // float4 index, 1048576 total
    int i = i4 * 4;
    int s = i >> 12, c = i & 4095, d = c & 127;
    f32x4 x = *(const f32x4*)(qf + i);
    f32x4 oth;
    if (d < 64) { f32x4 tt = *(const f32x4*)(qf + i + 64); oth = -tt; }
    else        { oth = *(const f32x4*)(qf + i - 64); }
    f32x4 cs = *(const f32x4*)(cosp + s * 128 + d);
    f32x4 sn = *(const f32x4*)(sinp + s * 128 + d);
    bf16x4 hv, lv;
#pragma unroll
    for (int j = 0; j < 4; j++) {
        float v = (x[j] * cs[j] + oth[j] * sn[j]) * 0.08838834764831845f; // /sqrt(128)
        bf16 h, l; split_bf(v, h, l);
        hv[j] = h; lv[j] = l;
    }
    *(bf16x4*)(qhi + i) = hv;
    *(bf16x4*)(qlo + i) = lv;
}

// RoPE on new k (fp32) -> ck_hi/ck_lo at l = 2048+s
__global__ void rope_k_kernel(const float* __restrict__ kf,
                              const float* __restrict__ cosp,
                              const float* __restrict__ sinp,
                              bf16* __restrict__ ckh, bf16* __restrict__ ckl)
{
    int i4 = blockIdx.x * 256 + threadIdx.x;  // 262144 total
    int i = i4 * 4;
    int s = i >> 10, c = i & 1023, kvh = c >> 7, d = c & 127;
    f32x4 x = *(const f32x4*)(kf + i);
    f32x4 oth;
    if (d < 64) { f32x4 tt = *(const f32x4*)(kf + i + 64); oth = -tt; }
    else        { oth = *(const f32x4*)(kf + i - 64); }
    f32x4 cs = *(const f32x4*)(cosp + s * 128 + d);
    f32x4 sn = *(const f32x4*)(sinp + s * 128 + d);
    bf16x4 hv, lv;
#pragma unroll
    for (int j = 0; j < 4; j++) {
        float v = x[j] * cs[j] + oth[j] * sn[j];
        bf16 h, l; split_bf(v, h, l);
        hv[j] = h; lv[j] = l;
    }
    size_t dst = ((size_t)kvh * LCTX + PASTN + s) * DHEAD + d;
    *(bf16x4*)(ckh + dst) = hv;
    *(bf16x4*)(ckl + dst) = lv;
}

// cached kv (l<2048) fp32 -> ck_hi/ck_lo (K) and cv (V)
__global__ void cache_conv_kernel(const float* __restrict__ kvp,
                                  const int* __restrict__ layer,
                                  bf16* __restrict__ ckh, bf16* __restrict__ ckl,
                                  bf16* __restrict__ cv)
{
    int i4 = blockIdx.x * 256 + threadIdx.x;     // 1048576 total (K half then V half)
    int half = (i4 >= 524288) ? 1 : 0;
    int e = (i4 - half * 524288) * 4;            // index into [h][l<2048][d]
    int hh = e >> 18, rem = e & 262143, l = rem >> 7, d = rem & 127;
    int blk = l >> 4, rr = l & 15;
    size_t src = (((size_t)(layer[0] * 2 + half) * 256 + blk) * 8 + hh) * (16 * 128)
               + (size_t)rr * 128 + d;
    f32x4 x = *(const f32x4*)(kvp + src);
    size_t dst = ((size_t)hh * LCTX + l) * DHEAD + d;
    if (!half) {
        bf16x4 hv, lv;
#pragma unroll
        for (int j = 0; j < 4; j++) { bf16 h, lo; split_bf(x[j], h, lo); hv[j] = h; lv[j] = lo; }
        *(bf16x4*)(ckh + dst) = hv;
        *(bf16x4*)(ckl + dst) = lv;
    } else {
        bf16x4 hv;
#pragma unroll
        for (int j = 0; j < 4; j++) hv[j] = (bf16)x[j];
        *(bf16x4*)(cv + dst) = hv;
    }
}

// ---------------------------------------------------------------------------
// Flash attention. Block = (q-head, 64-row q tile), 4 waves x 16 rows.
// QK^T split-bf16 (3 MFMA terms), PV plain bf16, fp32 online softmax.
// ---------------------------------------------------------------------------
__global__ __launch_bounds__(256, 2) void attn_kernel(
    const bf16* __restrict__ qhi, const bf16* __restrict__ qlo,
    const bf16* __restrict__ Kh, const bf16* __restrict__ Kl,
    const bf16* __restrict__ Vc, bf16* __restrict__ Og)
{
    const int h = blockIdx.x;
    const int s0 = blockIdx.y * 64;
    const int kvh = h >> 2;
    const int t = threadIdx.x, lane = t & 63, w = t >> 6;
    const int l16 = lane & 15, g16 = lane >> 4;

    __shared__ bf16 Ksh[64 * 128];
    __shared__ bf16 Ksl[64 * 128];
    __shared__ bf16 Vt[128 * 64];
    __shared__ bf16 Pl[4][16 * 64];

    // Q fragments in registers (hi+lo), rows = s0 + w*16 + (lane&15)
    bf16x8 qh[4], ql[4];
    {
        int row = s0 + w * 16 + l16;
        size_t base = (size_t)row * HIDN + (size_t)h * DHEAD;
#pragma unroll
        for (int kk = 0; kk < 4; kk++) {
            size_t off = base + kk * 32 + g16 * 8;
            qh[kk] = *(const bf16x8*)(qhi + off);
            ql[kk] = *(const bf16x8*)(qlo + off);
        }
    }

    f32x4 of[8];
#pragma unroll
    for (int cf = 0; cf < 8; cf++) of[cf] = (f32x4){0.f, 0.f, 0.f, 0.f};
    float mr[4], lr[4];
#pragma unroll
    for (int r = 0; r < 4; r++) { mr[r] = -3.0e38f; lr[r] = 0.f; }

    const bf16* Kbh = Kh + (size_t)kvh * LCTX * DHEAD;
    const bf16* Kbl = Kl + (size_t)kvh * LCTX * DHEAD;
    const bf16* Vb  = Vc + (size_t)kvh * LCTX * DHEAD;

    const int nt = (PASTN + s0 + 64) >> 6;

    for (int it = 0; it < nt; ++it) {
        const int l0 = it << 6;
        // ---- stage K (hi/lo) and V^T ----
#pragma unroll
        for (int i = 0; i < 4; i++) {
            int u = i * 256 + t;
            int row = u >> 4, g = u & 15;  // kv row 0..63, 8-elem granule 0..15
            size_t goff = (size_t)(l0 + row) * DHEAD + g * 8;
            bf16x8 vh = *(const bf16x8*)(Kbh + goff);
            bf16x8 vl = *(const bf16x8*)(Kbl + goff);
            bf16x8 vv = *(const bf16x8*)(Vb + goff);
            int la = row * 128 + ((g ^ (row & 7)) << 3);
            *(bf16x8*)&Ksh[la] = vh;
            *(bf16x8*)&Ksl[la] = vl;
#pragma unroll
            for (int j = 0; j < 8; j++) {
                int d = g * 8 + j;
                Vt[d * 64 + ((((row >> 3)) ^ (d & 7)) << 3) + (row & 7)] = vv[j];
            }
        }
        __syncthreads();

        // ---- S = Q K^T (split, scale pre-folded into q) ----
        f32x4 sf[4];
#pragma unroll
        for (int ni = 0; ni < 4; ni++) sf[ni] = (f32x4){0.f, 0.f, 0.f, 0.f};
#pragma unroll
        for (int ni = 0; ni < 4; ni++) {
#pragma unroll
            for (int kk = 0; kk < 4; kk++) {
                int r = ni * 16 + l16;      // kv row
                int g = kk * 4 + g16;       // d granule
                int la = r * 128 + ((g ^ (r & 7)) << 3);
                bf16x8 bh = *(bf16x8*)&Ksh[la];
                bf16x8 bl = *(bf16x8*)&Ksl[la];
                sf[ni] = mfma16(qh[kk], bh, sf[ni]);
                sf[ni] = mfma16(ql[kk], bh, sf[ni]);
                sf[ni] = mfma16(qh[kk], bl, sf[ni]);
            }
        }

        const bool needmask = (l0 + 63 > PASTN + s0);
        // ---- online softmax (per row r; row = s0 + w*16 + g16*4 + r) ----
#pragma unroll
        for (int r = 0; r < 4; r++) {
            int srow = s0 + w * 16 + (g16 << 2) + r;
            if (needmask) {
#pragma unroll
                for (int ni = 0; ni < 4; ni++) {
                    int col = l0 + ni * 16 + l16;
                    if (col > PASTN + srow) sf[ni][r] = -3.0e38f;
                }
            }
            float mx = fmaxf(fmaxf(sf[0][r], sf[1][r]), fmaxf(sf[2][r], sf[3][r]));
            mx = fmaxf(mx, __shfl_xor(mx, 1));
            mx = fmaxf(mx, __shfl_xor(mx, 2));
            mx = fmaxf(mx, __shfl_xor(mx, 4));
            mx = fmaxf(mx, __shfl_xor(mx, 8));
            float mN = fmaxf(mr[r], mx);
            float corr = __expf(mr[r] - mN);
            mr[r] = mN;
            float ss = 0.f;
#pragma unroll
            for (int ni = 0; ni < 4; ni++) {
                float p = __expf(sf[ni][r] - mN);
                sf[ni][r] = p;
                ss += p;
            }
            ss += __shfl_xor(ss, 1);
            ss += __shfl_xor(ss, 2);
            ss += __shfl_xor(ss, 4);
            ss += __shfl_xor(ss, 8);
            lr[r] = lr[r] * corr + ss;
#pragma unroll
            for (int cf = 0; cf < 8; cf++) of[cf][r] = of[cf][r] * corr;
        }

        // ---- P -> wave-private LDS (bf16, swizzled for A-frag reads) ----
#pragma unroll
        for (int ni = 0; ni < 4; ni++)
#pragma unroll
            for (int r = 0; r < 4; r++) {
                int row = (g16 << 2) + r;
                int col = ni * 16 + l16;
                Pl[w][row * 64 + (((col >> 3) ^ (row & 7)) << 3) + (col & 7)] =
                    (bf16)sf[ni][r];
            }

        // ---- O += P @ V ----
#pragma unroll
        for (int ks = 0; ks < 2; ks++) {
            int g = ks * 4 + g16;
            int la = l16 * 64 + ((g ^ (l16 & 7)) << 3);
            bf16x8 pa = *(bf16x8*)&Pl[w][la];
#pragma unroll
            for (int cf = 0; cf < 8; cf++) {
                int rv = cf * 16 + l16;
                bf16x8 vb = *(bf16x8*)&Vt[rv * 64 + ((g ^ (rv & 7)) << 3)];
                of[cf] = mfma16(pa, vb, of[cf]);
            }
        }
        __syncthreads();
    }

    // ---- normalize + write o (bf16) ----
#pragma unroll
    for (int cf = 0; cf < 8; cf++)
#pragma unroll
        for (int r = 0; r < 4; r++) {
            int srow = s0 + w * 16 + (g16 << 2) + r;
            int d = cf * 16 + l16;
            Og[(size_t)srow * HIDN + (size_t)h * DHEAD + d] = (bf16)(of[cf][r] / lr[r]);
        }
}

// ---------------------------------------------------------------------------
// launcher
// ---------------------------------------------------------------------------
extern "C" void kernel_launch(void* const* d_in, const int* in_sizes, int n_in,
                              void* d_out, int out_size, void* d_ws, size_t ws_size,
                              hipStream_t stream)
{
    const float* hidden = (const float*)d_in[0];
    const float* kvp    = (const float*)d_in[1];
    const float* cosp   = (const float*)d_in[7];
    const float* sinp   = (const float*)d_in[8];
    const float* Wq     = (const float*)d_in[9];
    const float* Wk     = (const float*)d_in[10];
    const float* Wv     = (const float*)d_in[11];
    const float* Wo     = (const float*)d_in[12];
    const int*   layer  = (const int*)d_in[13];

    // workspace layout (48.2 MB total)
    char* ws = (char*)d_ws;
    float* kf32 = (float*)(ws);                         //  4,194,304 B
    bf16*  q_hi = (bf16*)(ws + 4194304);                //  8,388,608
    bf16*  q_lo = (bf16*)(ws + 12582912);               //  8,388,608
    bf16*  ckh  = (bf16*)(ws + 20971520);               //  6,291,456
    bf16*  ckl  = (bf16*)(ws + 27262976);               //  6,291,456
    bf16*  cv   = (bf16*)(ws + 33554432);               //  6,291,456
    bf16*  obuf = (bf16*)(ws + 39845888);               //  8,388,608

    float* qf32 = (float*)d_out;  // d_out doubles as fp32 q scratch, overwritten at the end

    // 1) fused QKV projection (split-bf16), N = 4096(Q)+1024(K)+1024(V)
    gemm_bt<3, 0, false><<<dim3(48, 8), 256, 0, stream>>>(
        hidden, Wq, Wk, Wv, qf32, kf32, cv, 1024, 6144, 4096);

    // 2) RoPE + hi/lo split
    rope_q_kernel<<<4096, 256, 0, stream>>>(qf32, cosp, sinp, q_hi, q_lo);
    rope_k_kernel<<<1024, 256, 0, stream>>>(kf32, cosp, sinp, ckh, ckl);

    // 3) cached KV -> bf16 (hi/lo for K)
    cache_conv_kernel<<<4096, 256, 0, stream>>>(kvp, layer, ckh, ckl, cv);

    // 4) flash attention
    attn_kernel<<<dim3(32, 16), 256, 0, stream>>>(q_hi, q_lo, ckh, ckl, cv, obuf);

    // 5) output projection (plain bf16)
    gemm_bt<1, 1, true><<<dim3(32, 8), 256, 0, stream>>>(
        obuf, Wo, nullptr, nullptr, (float*)d_out, nullptr, nullptr, 1024, 4096, 4096);
}

// Round 2
// 484.715 us; speedup vs baseline: 1.6874x; 1.6874x over previous
//
#include <hip/hip_runtime.h>
#include <cstdint>
#include <cstddef>

// ---------------------------------------------------------------------------
// L4maAttention, fp16 pipeline:
//   cvt fp32->fp16 (hidden, Wq,Wk,Wv) -> fused QKV GEMM (global_load_lds,
//   swizzled LDS) -> RoPE(q in-place, k->cache) -> cached-KV convert ->
//   flash attention (fp16, 1-term QK) -> O-proj GEMM -> d_out fp32.
// ---------------------------------------------------------------------------

typedef _Float16 f16;
typedef f16 f16x8 __attribute__((ext_vector_type(8)));
typedef f16 f16x4 __attribute__((ext_vector_type(4)));
typedef float f32x4 __attribute__((ext_vector_type(4)));

#define HIDN 4096
#define LCTX 3072
#define PASTN 2048
#define QK_SCALE 0.08838834764831845f   /* 1/sqrt(128) */

__device__ __forceinline__ f32x4 mfma16(f16x8 a, f16x8 b, f32x4 c) {
    return __builtin_amdgcn_mfma_f32_16x16x32_f16(a, b, c, 0, 0, 0);
}

// global -> LDS direct copy, 16B per lane. LDS dest is wave-uniform base
// + lane*16 (linear); swizzling is done on the per-lane GLOBAL address.
__device__ __forceinline__ void gl_lds16(const void* g, void* l) {
    auto gp = (const __attribute__((address_space(1))) unsigned int*)(uintptr_t)g;
    auto lp = (__attribute__((address_space(3))) unsigned int*)(uintptr_t)l;
    __builtin_amdgcn_global_load_lds(gp, lp, 16, 0, 0);
}

// ---------------------------------------------------------------------------
// fp32 -> fp16 conversion (vectorized)
// ---------------------------------------------------------------------------
__global__ void cvt_f32_f16(const float* __restrict__ src, f16* __restrict__ dst, int n4)
{
    int i = blockIdx.x * 256 + threadIdx.x;
    if (i >= n4) return;
    f32x4 v = *(const f32x4*)(src + (size_t)i * 4);
    f16x4 h;
#pragma unroll
    for (int j = 0; j < 4; j++) h[j] = (f16)v[j];
    *(f16x4*)(dst + (size_t)i * 4) = h;
}

// ---------------------------------------------------------------------------
// GEMM: C[M,N] = A[M,K] @ B[N,K]^T, both fp16 row-major.
// 128x128 tile, BK=64, 4 waves (2x2 of 64x64). global_load_lds staging with
// XOR-swizzled source granules; swizzled ds_read_b128 fragment loads.
// EPI 0: QKV epilogue (q fp16, k fp16, v -> cache). EPI 1: fp32 C.
// ---------------------------------------------------------------------------
template <int EPI>
__global__ __launch_bounds__(256, 3) void gemm_f16(
    const f16* __restrict__ A, const f16* __restrict__ B,
    float* __restrict__ Cf, f16* __restrict__ Cq, f16* __restrict__ Ck,
    f16* __restrict__ Cv, int M, int N, int K)
{
    __shared__ f16 As[128 * 64];
    __shared__ f16 Bs[128 * 64];

    const int t = threadIdx.x, lane = t & 63, w = t >> 6;
    const int wm = w >> 1, wn = w & 1;
    const int l16 = lane & 15, g16 = lane >> 4;
    const int m0 = blockIdx.y * 128, n0 = blockIdx.x * 128;

    // staging: each wave covers 32 rows (4 loads x 8 rows); lane -> (row, granule)
    const int srow = lane >> 3;             // 0..7 row within 8-row group
    const int sgr  = (lane & 7) ^ srow;     // swizzled source granule (16B)

    const size_t aoff = (size_t)(m0 + w * 32 + srow) * K + sgr * 8;
    const size_t boff = (size_t)(n0 + w * 32 + srow) * K + sgr * 8;

    f32x4 acc[4][4];
#pragma unroll
    for (int i = 0; i < 4; i++)
#pragma unroll
        for (int j = 0; j < 4; j++) acc[i][j] = (f32x4){0.f, 0.f, 0.f, 0.f};

    for (int k0 = 0; k0 < K; k0 += 64) {
#pragma unroll
        for (int j = 0; j < 4; j++) {
            gl_lds16(A + aoff + (size_t)j * 8 * K + k0, (void*)(As + (w * 32 + j * 8) * 64));
            gl_lds16(B + boff + (size_t)j * 8 * K + k0, (void*)(Bs + (w * 32 + j * 8) * 64));
        }
        __syncthreads();

#pragma unroll
        for (int ks = 0; ks < 2; ks++) {
            f16x8 af[4], bfr[4];
#pragma unroll
            for (int mi = 0; mi < 4; mi++) {
                int r = wm * 64 + mi * 16 + l16;
                int g = ks * 4 + g16;
                af[mi] = *(const f16x8*)&As[r * 64 + ((g ^ (r & 7)) << 3)];
            }
#pragma unroll
            for (int ni = 0; ni < 4; ni++) {
                int r = wn * 64 + ni * 16 + l16;
                int g = ks * 4 + g16;
                bfr[ni] = *(const f16x8*)&Bs[r * 64 + ((g ^ (r & 7)) << 3)];
            }
#pragma unroll
            for (int ni = 0; ni < 4; ni++)
#pragma unroll
                for (int mi = 0; mi < 4; mi++)
                    acc[mi][ni] = mfma16(af[mi], bfr[ni], acc[mi][ni]);
        }
        __syncthreads();
    }

#pragma unroll
    for (int mi = 0; mi < 4; mi++)
#pragma unroll
        for (int ni = 0; ni < 4; ni++)
#pragma unroll
            for (int r = 0; r < 4; r++) {
                int row = m0 + wm * 64 + mi * 16 + (g16 << 2) + r;
                int col = n0 + wn * 64 + ni * 16 + l16;
                float val = acc[mi][ni][r];
                if (EPI == 0) {
                    if (col < 4096) {
                        Cq[(size_t)row * 4096 + col] = (f16)val;
                    } else if (col < 5120) {
                        Ck[(size_t)row * 1024 + (col - 4096)] = (f16)val;
                    } else {
                        int c = col - 5120;
                        int hh = c >> 7, d = c & 127;
                        Cv[((size_t)hh * LCTX + PASTN + row) * 128 + d] = (f16)val;
                    }
                } else {
                    Cf[(size_t)row * N + col] = val;
                }
            }
}

// ---------------------------------------------------------------------------
// RoPE on q, in place (thread owns a (d, d+64) granule pair), scale folded in.
// ---------------------------------------------------------------------------
__global__ void rope_q(f16* __restrict__ q, const float* __restrict__ cosp,
                       const float* __restrict__ sinp)
{
    int i = blockIdx.x * 256 + threadIdx.x;   // 262144 = 1024 s * 32 h * 8 gd
    int gd = i & 7, hh = (i >> 3) & 31, s = i >> 8;
    size_t b1 = (size_t)s * 4096 + hh * 128 + gd * 8;
    f16x8 x1 = *(f16x8*)(q + b1);
    f16x8 x2 = *(f16x8*)(q + b1 + 64);
    const float* c1 = cosp + s * 128 + gd * 8;
    const float* s1 = sinp + s * 128 + gd * 8;
    const float* c2 = c1 + 64;
    const float* s2 = s1 + 64;
    f16x8 o1, o2;
#pragma unroll
    for (int j = 0; j < 8; j++) {
        float a = (float)x1[j], b = (float)x2[j];
        o1[j] = (f16)((a * c1[j] - b * s1[j]) * QK_SCALE);
        o2[j] = (f16)((b * c2[j] + a * s2[j]) * QK_SCALE);
    }
    *(f16x8*)(q + b1) = o1;
    *(f16x8*)(q + b1 + 64) = o2;
}

// RoPE on new k -> cache at l = 2048+s (no scale)
__global__ void rope_k(const f16* __restrict__ kraw, const float* __restrict__ cosp,
                       const float* __restrict__ sinp, f16* __restrict__ ck)
{
    int i = blockIdx.x * 256 + threadIdx.x;   // 65536 = 1024 s * 8 kvh * 8 gd
    int gd = i & 7, kvh = (i >> 3) & 7, s = i >> 6;
    size_t b1 = (size_t)s * 1024 + kvh * 128 + gd * 8;
    f16x8 x1 = *(const f16x8*)(kraw + b1);
    f16x8 x2 = *(const f16x8*)(kraw + b1 + 64);
    const float* c1 = cosp + s * 128 + gd * 8;
    const float* s1 = sinp + s * 128 + gd * 8;
    const float* c2 = c1 + 64;
    const float* s2 = s1 + 64;
    f16x8 o1, o2;
#pragma unroll
    for (int j = 0; j < 8; j++) {
        float a = (float)x1[j], b = (float)x2[j];
        o1[j] = (f16)(a * c1[j] - b * s1[j]);
        o2[j] = (f16)(b * c2[j] + a * s2[j]);
    }
    size_t dst = ((size_t)kvh * LCTX + PASTN + s) * 128 + gd * 8;
    *(f16x8*)(ck + dst) = o1;
    *(f16x8*)(ck + dst + 64) = o2;
}

// cached kv (l<2048) fp32 -> ck / cv fp16
__global__ void cache_conv(const float* __restrict__ kvp, const int* __restrict__ layer,
                           f16* __restrict__ ck, f16* __restrict__ cv)
{
    int i4 = blockIdx.x * 256 + threadIdx.x;   // 1048576 (K half then V half)
    int half = i4 >> 19;
    int e = (i4 & 524287) * 4;
    int hh = e >> 18, rem = e & 262143, l = rem >> 7, d = rem & 127;
    int blk = l >> 4, rr = l & 15;
    size_t src = (((size_t)(layer[0] * 2 + half) * 256 + blk) * 8 + hh) * 2048
               + (size_t)rr * 128 + d;
    f32x4 x = *(const f32x4*)(kvp + src);
    f16x4 h;
#pragma unroll
    for (int j = 0; j < 4; j++) h[j] = (f16)x[j];
    size_t dst = ((size_t)hh * LCTX + l) * 128 + d;
    *(f16x4*)((half ? cv : ck) + dst) = h;
}

// ---------------------------------------------------------------------------
// Flash attention. Block = (head, 64-row q tile), 4 waves x 16 rows.
// K staged via global_load_lds (swizzled source); V reg-staged + transposed
// scatter; fp32 online softmax; fp16 P and PV.
// ---------------------------------------------------------------------------
__global__ __launch_bounds__(256, 2) void attn_f16(
    const f16* __restrict__ Q, const f16* __restrict__ Kc,
    const f16* __restrict__ Vc, f16* __restrict__ Og)
{
    const int h = blockIdx.x, s0 = blockIdx.y * 64, kvh = h >> 2;
    const int t = threadIdx.x, lane = t & 63, w = t >> 6;
    const int l16 = lane & 15, g16 = lane >> 4;

    __shared__ f16 Ks[64 * 128];
    __shared__ f16 Vt[128 * 64];
    __shared__ f16 Pl[4][16 * 64];

    // Q fragments in registers; rows = s0 + w*16 + l16
    f16x8 qf[4];
    {
        size_t base = (size_t)(s0 + w * 16 + l16) * 4096 + h * 128;
#pragma unroll
        for (int kk = 0; kk < 4; kk++)
            qf[kk] = *(const f16x8*)(Q + base + kk * 32 + g16 * 8);
    }

    f32x4 of[8];
#pragma unroll
    for (int cf = 0; cf < 8; cf++) of[cf] = (f32x4){0.f, 0.f, 0.f, 0.f};
    float mr[4], lr[4];
#pragma unroll
    for (int r = 0; r < 4; r++) { mr[r] = -3.0e38f; lr[r] = 0.f; }

    const f16* Kb = Kc + (size_t)kvh * LCTX * 128;
    const f16* Vb = Vc + (size_t)kvh * LCTX * 128;
    const int nt = (PASTN + s0 + 64) >> 6;

    const int krow = lane >> 4;      // 0..3 (row within a 4-row K load)
    const int kp   = lane & 15;      // 16B granule position

    for (int it = 0; it < nt; ++it) {
        const int l0 = it << 6;

        // ---- stage K via global_load_lds (4 loads/wave, 4 rows each) ----
#pragma unroll
        for (int j = 0; j < 4; j++) {
            int r7 = ((j & 1) << 2) + krow;          // (row & 7)
            int sg = kp ^ r7;                        // swizzled src granule
            gl_lds16(Kb + (size_t)(l0 + w * 16 + j * 4 + krow) * 128 + sg * 8,
                     (void*)(Ks + (w * 16 + j * 4) * 128));
        }
        // ---- stage V^T (reg + transposed swizzled scatter) ----
#pragma unroll
        for (int i = 0; i < 4; i++) {
            int u = i * 256 + t;
            int row = u >> 4, g = u & 15;
            f16x8 vv = *(const f16x8*)(Vb + (size_t)(l0 + row) * 128 + g * 8);
#pragma unroll
            for (int j2 = 0; j2 < 8; j2++) {
                int d = g * 8 + j2;
                Vt[d * 64 + (((row >> 3) ^ (d & 7)) << 3) + (row & 7)] = vv[j2];
            }
        }
        __syncthreads();

        // ---- S = Q K^T ----
        f32x4 sf[4];
#pragma unroll
        for (int ni = 0; ni < 4; ni++) sf[ni] = (f32x4){0.f, 0.f, 0.f, 0.f};
#pragma unroll
        for (int ni = 0; ni < 4; ni++)
#pragma unroll
            for (int kk = 0; kk < 4; kk++) {
                int r = ni * 16 + l16;
                int g = kk * 4 + g16;
                f16x8 bh = *(const f16x8*)&Ks[r * 128 + ((g ^ (r & 7)) << 3)];
                sf[ni] = mfma16(qf[kk], bh, sf[ni]);
            }

        const bool needmask = (l0 + 63 > PASTN + s0);
#pragma unroll
        for (int r = 0; r < 4; r++) {
            int srow = s0 + w * 16 + (g16 << 2) + r;
            if (needmask) {
#pragma unroll
                for (int ni = 0; ni < 4; ni++) {
                    int col = l0 + ni * 16 + l16;
                    if (col > PASTN + srow) sf[ni][r] = -3.0e38f;
                }
            }
            float mx = fmaxf(fmaxf(sf[0][r], sf[1][r]), fmaxf(sf[2][r], sf[3][r]));
            mx = fmaxf(mx, __shfl_xor(mx, 1));
            mx = fmaxf(mx, __shfl_xor(mx, 2));
            mx = fmaxf(mx, __shfl_xor(mx, 4));
            mx = fmaxf(mx, __shfl_xor(mx, 8));
            float mN = fmaxf(mr[r], mx);
            float corr = __expf(mr[r] - mN);
            mr[r] = mN;
            float ss = 0.f;
#pragma unroll
            for (int ni = 0; ni < 4; ni++) {
                float p = __expf(sf[ni][r] - mN);
                sf[ni][r] = p;
                ss += p;
            }
            ss += __shfl_xor(ss, 1);
            ss += __shfl_xor(ss, 2);
            ss += __shfl_xor(ss, 4);
            ss += __shfl_xor(ss, 8);
            lr[r] = lr[r] * corr + ss;
#pragma unroll
            for (int cf = 0; cf < 8; cf++) of[cf][r] = of[cf][r] * corr;
        }

        // ---- P -> wave-private LDS (fp16, swizzled) ----
#pragma unroll
        for (int ni = 0; ni < 4; ni++)
#pragma unroll
            for (int r = 0; r < 4; r++) {
                int row = (g16 << 2) + r;
                int col = ni * 16 + l16;
                Pl[w][row * 64 + (((col >> 3) ^ (row & 7)) << 3) + (col & 7)] =
                    (f16)sf[ni][r];
            }

        // ---- O += P @ V ----
#pragma unroll
        for (int ks = 0; ks < 2; ks++) {
            int g = ks * 4 + g16;
            f16x8 pa = *(const f16x8*)&Pl[w][l16 * 64 + ((g ^ (l16 & 7)) << 3)];
#pragma unroll
            for (int cf = 0; cf < 8; cf++) {
                int rv = cf * 16 + l16;
                f16x8 vb = *(const f16x8*)&Vt[rv * 64 + ((g ^ (rv & 7)) << 3)];
                of[cf] = mfma16(pa, vb, of[cf]);
            }
        }
        __syncthreads();
    }

    // ---- normalize + write o (fp16) ----
#pragma unroll
    for (int cf = 0; cf < 8; cf++)
#pragma unroll
        for (int r = 0; r < 4; r++) {
            int srow = s0 + w * 16 + (g16 << 2) + r;
            int d = cf * 16 + l16;
            Og[(size_t)srow * 4096 + (size_t)h * 128 + d] = (f16)(of[cf][r] / lr[r]);
        }
}

// ---------------------------------------------------------------------------
// launcher
// ---------------------------------------------------------------------------
extern "C" void kernel_launch(void* const* d_in, const int* in_sizes, int n_in,
                              void* d_out, int out_size, void* d_ws, size_t ws_size,
                              hipStream_t stream)
{
    const float* hidden = (const float*)d_in[0];
    const float* kvp    = (const float*)d_in[1];
    const float* cosp   = (const float*)d_in[7];
    const float* sinp   = (const float*)d_in[8];
    const float* Wq     = (const float*)d_in[9];
    const float* Wk     = (const float*)d_in[10];
    const float* Wv     = (const float*)d_in[11];
    const float* Wo     = (const float*)d_in[12];
    const int*   layer  = (const int*)d_in[13];

    // workspace layout (~76 MB)
    char* ws = (char*)d_ws;
    f16* w16  = (f16*)ws;                   // 50,331,648 B (Wqkv; later reused for Wo)
    f16* h16  = (f16*)(ws + 50331648);      //  8,388,608
    f16* ck   = (f16*)(ws + 58720256);      //  6,291,456
    f16* cv   = (f16*)(ws + 65011712);      //  6,291,456
    f16* obuf = (f16*)(ws + 71303168);      //  8,388,608  -> end 79,691,776

    f16* q16  = (f16*)d_out;                      // 8 MB scratch inside d_out
    f16* kraw = (f16*)((char*)d_out + 8388608);   // 2 MB

    // 1) fp32 -> fp16 conversions
    cvt_f32_f16<<<4096,  256, 0, stream>>>(hidden, h16, 1048576);
    cvt_f32_f16<<<16384, 256, 0, stream>>>(Wq, w16, 4194304);
    cvt_f32_f16<<<4096,  256, 0, stream>>>(Wk, w16 + (size_t)4096 * 4096, 1048576);
    cvt_f32_f16<<<4096,  256, 0, stream>>>(Wv, w16 + (size_t)5120 * 4096, 1048576);

    // 2) fused QKV projection
    gemm_f16<0><<<dim3(48, 8), 256, 0, stream>>>(
        h16, w16, nullptr, q16, kraw, cv, 1024, 6144, 4096);

    // 3) Wo conversion (reuses w16; stream-ordered after QKV GEMM)
    cvt_f32_f16<<<16384, 256, 0, stream>>>(Wo, w16, 4194304);

    // 4) RoPE + cache population
    rope_q<<<1024, 256, 0, stream>>>(q16, cosp, sinp);
    rope_k<<<256, 256, 0, stream>>>(kraw, cosp, sinp, ck);
    cache_conv<<<4096, 256, 0, stream>>>(kvp, layer, ck, cv);

    // 5) flash attention
    attn_f16<<<dim3(32, 16), 256, 0, stream>>>(q16, ck, cv, obuf);

    // 6) output projection -> d_out fp32
    gemm_f16<1><<<dim3(32, 8), 256, 0, stream>>>(
        obuf, w16, (float*)d_out, nullptr, nullptr, nullptr, 1024, 4096, 4096);
}

// Round 3
// 337.512 us; speedup vs baseline: 2.4233x; 1.4361x over previous
//
#include <hip/hip_runtime.h>
#include <cstdint>
#include <cstddef>

// ---------------------------------------------------------------------------
// L4maAttention, fp16 pipeline:
//   cvt fp32->fp16 (hidden, Wq,Wk,Wv) -> fused QKV GEMM (global_load_lds,
//   swizzled LDS) -> RoPE(q in-place, k->cache) -> cached-KV convert ->
//   flash attention (fp16; V staged subtiled for ds_read_b64_tr_b16) ->
//   O-proj GEMM -> d_out fp32.
// ---------------------------------------------------------------------------

typedef _Float16 f16;
typedef f16 f16x8 __attribute__((ext_vector_type(8)));
typedef f16 f16x4 __attribute__((ext_vector_type(4)));
typedef float f32x4 __attribute__((ext_vector_type(4)));

#define HIDN 4096
#define LCTX 3072
#define PASTN 2048
#define QK_SCALE 0.08838834764831845f   /* 1/sqrt(128) */

__device__ __forceinline__ f32x4 mfma16(f16x8 a, f16x8 b, f32x4 c) {
    return __builtin_amdgcn_mfma_f32_16x16x32_f16(a, b, c, 0, 0, 0);
}

// global -> LDS direct copy, 16B per lane. LDS dest = wave-uniform base +
// lane*16 (linear); per-lane permutation happens on the GLOBAL source address.
__device__ __forceinline__ void gl_lds16(const void* g, void* l) {
    auto gp = (const __attribute__((address_space(1))) unsigned int*)(uintptr_t)g;
    auto lp = (__attribute__((address_space(3))) unsigned int*)(uintptr_t)l;
    __builtin_amdgcn_global_load_lds(gp, lp, 16, 0, 0);
}

// low 32 bits of a generic pointer into __shared__ = LDS byte offset
__device__ __forceinline__ uint32_t lds_lo(const void* p) {
    return (uint32_t)(uintptr_t)p;
}

// hardware transpose read: lane l, elem j <- lds_f16[(addr/2 rounded to group)
// ... with per-lane addr = base + lane*8B: elem j = base_f16 + (l>>4)*64 + j*16 + (l&15)
#define TRRD(dst, va, OFF) \
    asm volatile("ds_read_b64_tr_b16 %0, %1 offset:" #OFF : "=v"(dst) : "v"(va))

// ---------------------------------------------------------------------------
// fp32 -> fp16 conversion (vectorized)
// ---------------------------------------------------------------------------
__global__ void cvt_f32_f16(const float* __restrict__ src, f16* __restrict__ dst, int n4)
{
    int i = blockIdx.x * 256 + threadIdx.x;
    if (i >= n4) return;
    f32x4 v = *(const f32x4*)(src + (size_t)i * 4);
    f16x4 h;
#pragma unroll
    for (int j = 0; j < 4; j++) h[j] = (f16)v[j];
    *(f16x4*)(dst + (size_t)i * 4) = h;
}

// ---------------------------------------------------------------------------
// GEMM: C[M,N] = A[M,K] @ B[N,K]^T, both fp16 row-major. (unchanged)
// ---------------------------------------------------------------------------
template <int EPI>
__global__ __launch_bounds__(256, 3) void gemm_f16(
    const f16* __restrict__ A, const f16* __restrict__ B,
    float* __restrict__ Cf, f16* __restrict__ Cq, f16* __restrict__ Ck,
    f16* __restrict__ Cv, int M, int N, int K)
{
    __shared__ f16 As[128 * 64];
    __shared__ f16 Bs[128 * 64];

    const int t = threadIdx.x, lane = t & 63, w = t >> 6;
    const int wm = w >> 1, wn = w & 1;
    const int l16 = lane & 15, g16 = lane >> 4;
    const int m0 = blockIdx.y * 128, n0 = blockIdx.x * 128;

    const int srow = lane >> 3;
    const int sgr  = (lane & 7) ^ srow;

    const size_t aoff = (size_t)(m0 + w * 32 + srow) * K + sgr * 8;
    const size_t boff = (size_t)(n0 + w * 32 + srow) * K + sgr * 8;

    f32x4 acc[4][4];
#pragma unroll
    for (int i = 0; i < 4; i++)
#pragma unroll
        for (int j = 0; j < 4; j++) acc[i][j] = (f32x4){0.f, 0.f, 0.f, 0.f};

    for (int k0 = 0; k0 < K; k0 += 64) {
#pragma unroll
        for (int j = 0; j < 4; j++) {
            gl_lds16(A + aoff + (size_t)j * 8 * K + k0, (void*)(As + (w * 32 + j * 8) * 64));
            gl_lds16(B + boff + (size_t)j * 8 * K + k0, (void*)(Bs + (w * 32 + j * 8) * 64));
        }
        __syncthreads();

#pragma unroll
        for (int ks = 0; ks < 2; ks++) {
            f16x8 af[4], bfr[4];
#pragma unroll
            for (int mi = 0; mi < 4; mi++) {
                int r = wm * 64 + mi * 16 + l16;
                int g = ks * 4 + g16;
                af[mi] = *(const f16x8*)&As[r * 64 + ((g ^ (r & 7)) << 3)];
            }
#pragma unroll
            for (int ni = 0; ni < 4; ni++) {
                int r = wn * 64 + ni * 16 + l16;
                int g = ks * 4 + g16;
                bfr[ni] = *(const f16x8*)&Bs[r * 64 + ((g ^ (r & 7)) << 3)];
            }
#pragma unroll
            for (int ni = 0; ni < 4; ni++)
#pragma unroll
                for (int mi = 0; mi < 4; mi++)
                    acc[mi][ni] = mfma16(af[mi], bfr[ni], acc[mi][ni]);
        }
        __syncthreads();
    }

#pragma unroll
    for (int mi = 0; mi < 4; mi++)
#pragma unroll
        for (int ni = 0; ni < 4; ni++)
#pragma unroll
            for (int r = 0; r < 4; r++) {
                int row = m0 + wm * 64 + mi * 16 + (g16 << 2) + r;
                int col = n0 + wn * 64 + ni * 16 + l16;
                float val = acc[mi][ni][r];
                if (EPI == 0) {
                    if (col < 4096) {
                        Cq[(size_t)row * 4096 + col] = (f16)val;
                    } else if (col < 5120) {
                        Ck[(size_t)row * 1024 + (col - 4096)] = (f16)val;
                    } else {
                        int c = col - 5120;
                        int hh = c >> 7, d = c & 127;
                        Cv[((size_t)hh * LCTX + PASTN + row) * 128 + d] = (f16)val;
                    }
                } else {
                    Cf[(size_t)row * N + col] = val;
                }
            }
}

// ---------------------------------------------------------------------------
// RoPE q (in place, scale folded), RoPE k -> cache, cached-KV convert
// (all unchanged from round 2)
// ---------------------------------------------------------------------------
__global__ void rope_q(f16* __restrict__ q, const float* __restrict__ cosp,
                       const float* __restrict__ sinp)
{
    int i = blockIdx.x * 256 + threadIdx.x;
    int gd = i & 7, hh = (i >> 3) & 31, s = i >> 8;
    size_t b1 = (size_t)s * 4096 + hh * 128 + gd * 8;
    f16x8 x1 = *(f16x8*)(q + b1);
    f16x8 x2 = *(f16x8*)(q + b1 + 64);
    const float* c1 = cosp + s * 128 + gd * 8;
    const float* s1 = sinp + s * 128 + gd * 8;
    const float* c2 = c1 + 64;
    const float* s2 = s1 + 64;
    f16x8 o1, o2;
#pragma unroll
    for (int j = 0; j < 8; j++) {
        float a = (float)x1[j], b = (float)x2[j];
        o1[j] = (f16)((a * c1[j] - b * s1[j]) * QK_SCALE);
        o2[j] = (f16)((b * c2[j] + a * s2[j]) * QK_SCALE);
    }
    *(f16x8*)(q + b1) = o1;
    *(f16x8*)(q + b1 + 64) = o2;
}

__global__ void rope_k(const f16* __restrict__ kraw, const float* __restrict__ cosp,
                       const float* __restrict__ sinp, f16* __restrict__ ck)
{
    int i = blockIdx.x * 256 + threadIdx.x;
    int gd = i & 7, kvh = (i >> 3) & 7, s = i >> 6;
    size_t b1 = (size_t)s * 1024 + kvh * 128 + gd * 8;
    f16x8 x1 = *(const f16x8*)(kraw + b1);
    f16x8 x2 = *(const f16x8*)(kraw + b1 + 64);
    const float* c1 = cosp + s * 128 + gd * 8;
    const float* s1 = sinp + s * 128 + gd * 8;
    const float* c2 = c1 + 64;
    const float* s2 = s1 + 64;
    f16x8 o1, o2;
#pragma unroll
    for (int j = 0; j < 8; j++) {
        float a = (float)x1[j], b = (float)x2[j];
        o1[j] = (f16)(a * c1[j] - b * s1[j]);
        o2[j] = (f16)(b * c2[j] + a * s2[j]);
    }
    size_t dst = ((size_t)kvh * LCTX + PASTN + s) * 128 + gd * 8;
    *(f16x8*)(ck + dst) = o1;
    *(f16x8*)(ck + dst + 64) = o2;
}

__global__ void cache_conv(const float* __restrict__ kvp, const int* __restrict__ layer,
                           f16* __restrict__ ck, f16* __restrict__ cv)
{
    int i4 = blockIdx.x * 256 + threadIdx.x;
    int half = i4 >> 19;
    int e = (i4 & 524287) * 4;
    int hh = e >> 18, rem = e & 262143, l = rem >> 7, d = rem & 127;
    int blk = l >> 4, rr = l & 15;
    size_t src = (((size_t)(layer[0] * 2 + half) * 256 + blk) * 8 + hh) * 2048
               + (size_t)rr * 128 + d;
    f32x4 x = *(const f32x4*)(kvp + src);
    f16x4 h;
#pragma unroll
    for (int j = 0; j < 4; j++) h[j] = (f16)x[j];
    size_t dst = ((size_t)hh * LCTX + l) * 128 + d;
    *(f16x4*)((half ? cv : ck) + dst) = h;
}

// ---------------------------------------------------------------------------
// Flash attention. Block = (head, 64-row q tile), 4 waves x 16 rows.
// K staged via global_load_lds (XOR-swizzled source). V staged via
// global_load_lds into the tr_b16-subtiled layout:
//   f(l,d) = (d&15) + (l&3)*16 + ((l>>3)&3)*64 + ((l>>2)&1)*256
//          + (d>>4)*512 + (l>>5)*4096         (f16 units, bijective on 64x128)
// PV B-fragments via ds_read_b64_tr_b16 (per-lane addr = base + lane*8B,
// offset imm = (cf*512 + r*256)*2 walks subtiles). Defer-max softmax (THR=8).
// ---------------------------------------------------------------------------
__global__ __launch_bounds__(256, 2) void attn_f16(
    const f16* __restrict__ Q, const f16* __restrict__ Kc,
    const f16* __restrict__ Vc, f16* __restrict__ Og)
{
    const int h = blockIdx.x, s0 = blockIdx.y * 64, kvh = h >> 2;
    const int t = threadIdx.x, lane = t & 63, w = t >> 6;
    const int l16 = lane & 15, g16 = lane >> 4;

    __shared__ f16 Ks[64 * 128];
    __shared__ f16 Vs[64 * 128];   // subtiled layout (see f(l,d) above)
    __shared__ f16 Pl[4][16 * 64];

    // Q fragments in registers; rows = s0 + w*16 + l16
    f16x8 qf[4];
    {
        size_t base = (size_t)(s0 + w * 16 + l16) * 4096 + h * 128;
#pragma unroll
        for (int kk = 0; kk < 4; kk++)
            qf[kk] = *(const f16x8*)(Q + base + kk * 32 + g16 * 8);
    }

    f32x4 of[8];
#pragma unroll
    for (int cf = 0; cf < 8; cf++) of[cf] = (f32x4){0.f, 0.f, 0.f, 0.f};
    float mr[4], lr[4];
#pragma unroll
    for (int r = 0; r < 4; r++) { mr[r] = -3.0e38f; lr[r] = 0.f; }

    const f16* Kb = Kc + (size_t)kvh * LCTX * 128;
    const f16* Vb = Vc + (size_t)kvh * LCTX * 128;
    const int nt = (PASTN + s0 + 64) >> 6;

    // K staging lane map (source-swizzled, like the GEMM)
    const int krow = lane >> 4;
    const int kp   = lane & 15;

    // V staging lane map: lane -> l within a 32-row half + 8-f16 d sub-offset
    const int lv = ((lane >> 3) & 3) * 8 + ((lane >> 5) & 1) * 4 + ((lane >> 1) & 3);
    const int vdo = (lane & 1) * 8;

    const uint32_t vs_lane = lds_lo(Vs) + lane * 8;  // tr-read per-lane base

    for (int it = 0; it < nt; ++it) {
        const int l0 = it << 6;

        // ---- stage K via global_load_lds (4 loads/wave, 4 rows each) ----
#pragma unroll
        for (int j = 0; j < 4; j++) {
            int r7 = ((j & 1) << 2) + krow;
            int sg = kp ^ r7;
            gl_lds16(Kb + (size_t)(l0 + w * 16 + j * 4 + krow) * 128 + sg * 8,
                     (void*)(Ks + (w * 16 + j * 4) * 128));
        }
        // ---- stage V via global_load_lds into subtiled layout ----
#pragma unroll
        for (int q = 0; q < 4; q++) {
            int idx = w * 4 + q;            // 0..15
            int ks = idx >> 3, db = idx & 7;
            gl_lds16(Vb + (size_t)(l0 + ks * 32 + lv) * 128 + db * 16 + vdo,
                     (void*)(Vs + ks * 4096 + db * 512));
        }
        __syncthreads();

        // ---- S = Q K^T ----
        f32x4 sf[4];
#pragma unroll
        for (int ni = 0; ni < 4; ni++) sf[ni] = (f32x4){0.f, 0.f, 0.f, 0.f};
#pragma unroll
        for (int ni = 0; ni < 4; ni++)
#pragma unroll
            for (int kk = 0; kk < 4; kk++) {
                int r = ni * 16 + l16;
                int g = kk * 4 + g16;
                f16x8 bh = *(const f16x8*)&Ks[r * 128 + ((g ^ (r & 7)) << 3)];
                sf[ni] = mfma16(qf[kk], bh, sf[ni]);
            }

        const bool needmask = (l0 + 63 > PASTN + s0);
#pragma unroll
        for (int r = 0; r < 4; r++) {
            int srow = s0 + w * 16 + (g16 << 2) + r;
            if (needmask) {
#pragma unroll
                for (int ni = 0; ni < 4; ni++) {
                    int col = l0 + ni * 16 + l16;
                    if (col > PASTN + srow) sf[ni][r] = -3.0e38f;
                }
            }
            float mx = fmaxf(fmaxf(sf[0][r], sf[1][r]), fmaxf(sf[2][r], sf[3][r]));
            mx = fmaxf(mx, __shfl_xor(mx, 1));
            mx = fmaxf(mx, __shfl_xor(mx, 2));
            mx = fmaxf(mx, __shfl_xor(mx, 4));
            mx = fmaxf(mx, __shfl_xor(mx, 8));
            // defer-max (T13): only rescale when the running max grew by >8
            if (mx > mr[r] + 8.0f) {
                float corr = __expf(mr[r] - mx);
                mr[r] = mx;
                lr[r] *= corr;
#pragma unroll
                for (int cf = 0; cf < 8; cf++) of[cf][r] *= corr;
            }
            float ss = 0.f;
#pragma unroll
            for (int ni = 0; ni < 4; ni++) {
                float p = __expf(sf[ni][r] - mr[r]);
                sf[ni][r] = p;
                ss += p;
            }
            ss += __shfl_xor(ss, 1);
            ss += __shfl_xor(ss, 2);
            ss += __shfl_xor(ss, 4);
            ss += __shfl_xor(ss, 8);
            lr[r] += ss;
        }

        // ---- P -> wave-private LDS (fp16, swizzled) ----
#pragma unroll
        for (int ni = 0; ni < 4; ni++)
#pragma unroll
            for (int r = 0; r < 4; r++) {
                int row = (g16 << 2) + r;
                int col = ni * 16 + l16;
                Pl[w][row * 64 + (((col >> 3) ^ (row & 7)) << 3) + (col & 7)] =
                    (f16)sf[ni][r];
            }

        // ---- O += P @ V  (V^T fragments via ds_read_b64_tr_b16) ----
#pragma unroll
        for (int ks = 0; ks < 2; ks++) {
            int g = ks * 4 + g16;
            f16x8 pa = *(const f16x8*)&Pl[w][l16 * 64 + ((g ^ (l16 & 7)) << 3)];
            uint32_t va = vs_lane + ks * 8192;
            f16x4 t0, t1, t2, t3, t4, t5, t6, t7;
            f16x4 u0, u1, u2, u3, u4, u5, u6, u7;
            TRRD(t0, va, 0);    TRRD(u0, va, 512);
            TRRD(t1, va, 1024); TRRD(u1, va, 1536);
            TRRD(t2, va, 2048); TRRD(u2, va, 2560);
            TRRD(t3, va, 3072); TRRD(u3, va, 3584);
            TRRD(t4, va, 4096); TRRD(u4, va, 4608);
            TRRD(t5, va, 5120); TRRD(u5, va, 5632);
            TRRD(t6, va, 6144); TRRD(u6, va, 6656);
            TRRD(t7, va, 7168); TRRD(u7, va, 7680);
            asm volatile("s_waitcnt lgkmcnt(0)" ::: "memory");
            __builtin_amdgcn_sched_barrier(0);
#define PV_MFMA(cf, lo, hi)                                        \
            {                                                      \
                f16x8 vb;                                          \
                vb[0] = lo[0]; vb[1] = lo[1]; vb[2] = lo[2];       \
                vb[3] = lo[3]; vb[4] = hi[0]; vb[5] = hi[1];       \
                vb[6] = hi[2]; vb[7] = hi[3];                      \
                of[cf] = mfma16(pa, vb, of[cf]);                   \
            }
            PV_MFMA(0, t0, u0) PV_MFMA(1, t1, u1)
            PV_MFMA(2, t2, u2) PV_MFMA(3, t3, u3)
            PV_MFMA(4, t4, u4) PV_MFMA(5, t5, u5)
            PV_MFMA(6, t6, u6) PV_MFMA(7, t7, u7)
#undef PV_MFMA
        }
        __syncthreads();
    }

    // ---- normalize + write o (fp16) ----
#pragma unroll
    for (int cf = 0; cf < 8; cf++)
#pragma unroll
        for (int r = 0; r < 4; r++) {
            int srow = s0 + w * 16 + (g16 << 2) + r;
            int d = cf * 16 + l16;
            Og[(size_t)srow * 4096 + (size_t)h * 128 + d] = (f16)(of[cf][r] / lr[r]);
        }
}

// ---------------------------------------------------------------------------
// launcher
// ---------------------------------------------------------------------------
extern "C" void kernel_launch(void* const* d_in, const int* in_sizes, int n_in,
                              void* d_out, int out_size, void* d_ws, size_t ws_size,
                              hipStream_t stream)
{
    const float* hidden = (const float*)d_in[0];
    const float* kvp    = (const float*)d_in[1];
    const float* cosp   = (const float*)d_in[7];
    const float* sinp   = (const float*)d_in[8];
    const float* Wq     = (const float*)d_in[9];
    const float* Wk     = (const float*)d_in[10];
    const float* Wv     = (const float*)d_in[11];
    const float* Wo     = (const float*)d_in[12];
    const int*   layer  = (const int*)d_in[13];

    char* ws = (char*)d_ws;
    f16* w16  = (f16*)ws;                   // 50,331,648 B (Wqkv; later reused for Wo)
    f16* h16  = (f16*)(ws + 50331648);      //  8,388,608
    f16* ck   = (f16*)(ws + 58720256);      //  6,291,456
    f16* cv   = (f16*)(ws + 65011712);      //  6,291,456
    f16* obuf = (f16*)(ws + 71303168);      //  8,388,608

    f16* q16  = (f16*)d_out;                      // 8 MB scratch inside d_out
    f16* kraw = (f16*)((char*)d_out + 8388608);   // 2 MB

    // 1) fp32 -> fp16 conversions
    cvt_f32_f16<<<4096,  256, 0, stream>>>(hidden, h16, 1048576);
    cvt_f32_f16<<<16384, 256, 0, stream>>>(Wq, w16, 4194304);
    cvt_f32_f16<<<4096,  256, 0, stream>>>(Wk, w16 + (size_t)4096 * 4096, 1048576);
    cvt_f32_f16<<<4096,  256, 0, stream>>>(Wv, w16 + (size_t)5120 * 4096, 1048576);

    // 2) fused QKV projection
    gemm_f16<0><<<dim3(48, 8), 256, 0, stream>>>(
        h16, w16, nullptr, q16, kraw, cv, 1024, 6144, 4096);

    // 3) Wo conversion (reuses w16)
    cvt_f32_f16<<<16384, 256, 0, stream>>>(Wo, w16, 4194304);

    // 4) RoPE + cache population
    rope_q<<<1024, 256, 0, stream>>>(q16, cosp, sinp);
    rope_k<<<256, 256, 0, stream>>>(kraw, cosp, sinp, ck);
    cache_conv<<<4096, 256, 0, stream>>>(kvp, layer, ck, cv);

    // 5) flash attention
    attn_f16<<<dim3(32, 16), 256, 0, stream>>>(q16, ck, cv, obuf);

    // 6) output projection -> d_out fp32
    gemm_f16<1><<<dim3(32, 8), 256, 0, stream>>>(
        obuf, w16, (float*)d_out, nullptr, nullptr, nullptr, 1024, 4096, 4096);
}

// Round 4
// 332.692 us; speedup vs baseline: 2.4584x; 1.0145x over previous
//
#include <hip/hip_runtime.h>
#include <cstdint>
#include <cstddef>

// ---------------------------------------------------------------------------
// L4maAttention, fp16 pipeline:
//   cvt fp32->fp16 (hidden, Wq,Wk,Wv) -> fused QKV GEMM (global_load_lds,
//   swizzled LDS) -> RoPE(q in-place, k->cache) -> cached-KV convert ->
//   flash attention (fp16; double-buffered staging; V via ds_read_b64_tr_b16;
//   balanced q-tile remap) -> O-proj GEMM -> d_out fp32.
// ---------------------------------------------------------------------------

typedef _Float16 f16;
typedef f16 f16x8 __attribute__((ext_vector_type(8)));
typedef f16 f16x4 __attribute__((ext_vector_type(4)));
typedef float f32x4 __attribute__((ext_vector_type(4)));

#define HIDN 4096
#define LCTX 3072
#define PASTN 2048
#define QK_SCALE 0.08838834764831845f   /* 1/sqrt(128) */

__device__ __forceinline__ f32x4 mfma16(f16x8 a, f16x8 b, f32x4 c) {
    return __builtin_amdgcn_mfma_f32_16x16x32_f16(a, b, c, 0, 0, 0);
}

// global -> LDS direct copy, 16B per lane. LDS dest = wave-uniform base +
// lane*16 (linear); per-lane permutation happens on the GLOBAL source address.
__device__ __forceinline__ void gl_lds16(const void* g, void* l) {
    auto gp = (const __attribute__((address_space(1))) unsigned int*)(uintptr_t)g;
    auto lp = (__attribute__((address_space(3))) unsigned int*)(uintptr_t)l;
    __builtin_amdgcn_global_load_lds(gp, lp, 16, 0, 0);
}

__device__ __forceinline__ uint32_t lds_lo(const void* p) {
    return (uint32_t)(uintptr_t)p;
}

// hardware transpose read (4x16 f16 subtile, column-major delivery)
#define TRRD(dst, va, OFF) \
    asm volatile("ds_read_b64_tr_b16 %0, %1 offset:" #OFF : "=v"(dst) : "v"(va))

// ---------------------------------------------------------------------------
// fp32 -> fp16 conversion (vectorized)
// ---------------------------------------------------------------------------
__global__ void cvt_f32_f16(const float* __restrict__ src, f16* __restrict__ dst, int n4)
{
    int i = blockIdx.x * 256 + threadIdx.x;
    if (i >= n4) return;
    f32x4 v = *(const f32x4*)(src + (size_t)i * 4);
    f16x4 h;
#pragma unroll
    for (int j = 0; j < 4; j++) h[j] = (f16)v[j];
    *(f16x4*)(dst + (size_t)i * 4) = h;
}

// ---------------------------------------------------------------------------
// GEMM: C[M,N] = A[M,K] @ B[N,K]^T, both fp16 row-major. (unchanged, m97-style)
// ---------------------------------------------------------------------------
template <int EPI>
__global__ __launch_bounds__(256, 3) void gemm_f16(
    const f16* __restrict__ A, const f16* __restrict__ B,
    float* __restrict__ Cf, f16* __restrict__ Cq, f16* __restrict__ Ck,
    f16* __restrict__ Cv, int M, int N, int K)
{
    __shared__ f16 As[128 * 64];
    __shared__ f16 Bs[128 * 64];

    const int t = threadIdx.x, lane = t & 63, w = t >> 6;
    const int wm = w >> 1, wn = w & 1;
    const int l16 = lane & 15, g16 = lane >> 4;
    const int m0 = blockIdx.y * 128, n0 = blockIdx.x * 128;

    const int srow = lane >> 3;
    const int sgr  = (lane & 7) ^ srow;

    const size_t aoff = (size_t)(m0 + w * 32 + srow) * K + sgr * 8;
    const size_t boff = (size_t)(n0 + w * 32 + srow) * K + sgr * 8;

    f32x4 acc[4][4];
#pragma unroll
    for (int i = 0; i < 4; i++)
#pragma unroll
        for (int j = 0; j < 4; j++) acc[i][j] = (f32x4){0.f, 0.f, 0.f, 0.f};

    for (int k0 = 0; k0 < K; k0 += 64) {
#pragma unroll
        for (int j = 0; j < 4; j++) {
            gl_lds16(A + aoff + (size_t)j * 8 * K + k0, (void*)(As + (w * 32 + j * 8) * 64));
            gl_lds16(B + boff + (size_t)j * 8 * K + k0, (void*)(Bs + (w * 32 + j * 8) * 64));
        }
        __syncthreads();

#pragma unroll
        for (int ks = 0; ks < 2; ks++) {
            f16x8 af[4], bfr[4];
#pragma unroll
            for (int mi = 0; mi < 4; mi++) {
                int r = wm * 64 + mi * 16 + l16;
                int g = ks * 4 + g16;
                af[mi] = *(const f16x8*)&As[r * 64 + ((g ^ (r & 7)) << 3)];
            }
#pragma unroll
            for (int ni = 0; ni < 4; ni++) {
                int r = wn * 64 + ni * 16 + l16;
                int g = ks * 4 + g16;
                bfr[ni] = *(const f16x8*)&Bs[r * 64 + ((g ^ (r & 7)) << 3)];
            }
#pragma unroll
            for (int ni = 0; ni < 4; ni++)
#pragma unroll
                for (int mi = 0; mi < 4; mi++)
                    acc[mi][ni] = mfma16(af[mi], bfr[ni], acc[mi][ni]);
        }
        __syncthreads();
    }

#pragma unroll
    for (int mi = 0; mi < 4; mi++)
#pragma unroll
        for (int ni = 0; ni < 4; ni++)
#pragma unroll
            for (int r = 0; r < 4; r++) {
                int row = m0 + wm * 64 + mi * 16 + (g16 << 2) + r;
                int col = n0 + wn * 64 + ni * 16 + l16;
                float val = acc[mi][ni][r];
                if (EPI == 0) {
                    if (col < 4096) {
                        Cq[(size_t)row * 4096 + col] = (f16)val;
                    } else if (col < 5120) {
                        Ck[(size_t)row * 1024 + (col - 4096)] = (f16)val;
                    } else {
                        int c = col - 5120;
                        int hh = c >> 7, d = c & 127;
                        Cv[((size_t)hh * LCTX + PASTN + row) * 128 + d] = (f16)val;
                    }
                } else {
                    Cf[(size_t)row * N + col] = val;
                }
            }
}

// ---------------------------------------------------------------------------
// RoPE q (in place, scale folded), RoPE k -> cache, cached-KV convert
// ---------------------------------------------------------------------------
__global__ void rope_q(f16* __restrict__ q, const float* __restrict__ cosp,
                       const float* __restrict__ sinp)
{
    int i = blockIdx.x * 256 + threadIdx.x;
    int gd = i & 7, hh = (i >> 3) & 31, s = i >> 8;
    size_t b1 = (size_t)s * 4096 + hh * 128 + gd * 8;
    f16x8 x1 = *(f16x8*)(q + b1);
    f16x8 x2 = *(f16x8*)(q + b1 + 64);
    const float* c1 = cosp + s * 128 + gd * 8;
    const float* s1 = sinp + s * 128 + gd * 8;
    const float* c2 = c1 + 64;
    const float* s2 = s1 + 64;
    f16x8 o1, o2;
#pragma unroll
    for (int j = 0; j < 8; j++) {
        float a = (float)x1[j], b = (float)x2[j];
        o1[j] = (f16)((a * c1[j] - b * s1[j]) * QK_SCALE);
        o2[j] = (f16)((b * c2[j] + a * s2[j]) * QK_SCALE);
    }
    *(f16x8*)(q + b1) = o1;
    *(f16x8*)(q + b1 + 64) = o2;
}

__global__ void rope_k(const f16* __restrict__ kraw, const float* __restrict__ cosp,
                       const float* __restrict__ sinp, f16* __restrict__ ck)
{
    int i = blockIdx.x * 256 + threadIdx.x;
    int gd = i & 7, kvh = (i >> 3) & 7, s = i >> 6;
    size_t b1 = (size_t)s * 1024 + kvh * 128 + gd * 8;
    f16x8 x1 = *(const f16x8*)(kraw + b1);
    f16x8 x2 = *(const f16x8*)(kraw + b1 + 64);
    const float* c1 = cosp + s * 128 + gd * 8;
    const float* s1 = sinp + s * 128 + gd * 8;
    const float* c2 = c1 + 64;
    const float* s2 = s1 + 64;
    f16x8 o1, o2;
#pragma unroll
    for (int j = 0; j < 8; j++) {
        float a = (float)x1[j], b = (float)x2[j];
        o1[j] = (f16)(a * c1[j] - b * s1[j]);
        o2[j] = (f16)(b * c2[j] + a * s2[j]);
    }
    size_t dst = ((size_t)kvh * LCTX + PASTN + s) * 128 + gd * 8;
    *(f16x8*)(ck + dst) = o1;
    *(f16x8*)(ck + dst + 64) = o2;
}

__global__ void cache_conv(const float* __restrict__ kvp, const int* __restrict__ layer,
                           f16* __restrict__ ck, f16* __restrict__ cv)
{
    int i4 = blockIdx.x * 256 + threadIdx.x;
    int half = i4 >> 19;
    int e = (i4 & 524287) * 4;
    int hh = e >> 18, rem = e & 262143, l = rem >> 7, d = rem & 127;
    int blk = l >> 4, rr = l & 15;
    size_t src = (((size_t)(layer[0] * 2 + half) * 256 + blk) * 8 + hh) * 2048
               + (size_t)rr * 128 + d;
    f32x4 x = *(const f32x4*)(kvp + src);
    f16x4 h;
#pragma unroll
    for (int j = 0; j < 4; j++) h[j] = (f16)x[j];
    size_t dst = ((size_t)hh * LCTX + l) * 128 + d;
    *(f16x4*)((half ? cv : ck) + dst) = h;
}

// ---------------------------------------------------------------------------
// Flash attention, 2-phase double-buffered.
// Grid: 512 blocks 1-D. Block b<256 -> (head = b&31, tile = b>>5);
// block b>=256 -> (head = b&31, tile = 15 - ((b-256)>>5)).  Round-robin
// dispatch puts blocks c and c+256 on the same CU -> each CU sums to a
// constant 81 KV-tiles (balances the causal-length skew).
// Per tile: issue next tile's global_load_lds into buf^1, compute on buf,
// __syncthreads() (drains vmcnt) -> load latency hides under compute.
// ---------------------------------------------------------------------------
__global__ __launch_bounds__(256, 2) void attn_f16(
    const f16* __restrict__ Q, const f16* __restrict__ Kc,
    const f16* __restrict__ Vc, f16* __restrict__ Og)
{
    const int b = blockIdx.x;
    const int idx = b & 255;
    const int h = idx & 31;
    const int jt = idx >> 5;
    const int tile = (b >> 8) ? (15 - jt) : jt;
    const int s0 = tile * 64;
    const int kvh = h >> 2;
    const int t = threadIdx.x, lane = t & 63, w = t >> 6;
    const int l16 = lane & 15, g16 = lane >> 4;

    __shared__ f16 Ks[2][64 * 128];
    __shared__ f16 Vs[2][64 * 128];   // tr_b16-subtiled layout
    __shared__ f16 Pl[4][16 * 64];

    // Q fragments in registers; rows = s0 + w*16 + l16
    f16x8 qf[4];
    {
        size_t base = (size_t)(s0 + w * 16 + l16) * 4096 + h * 128;
#pragma unroll
        for (int kk = 0; kk < 4; kk++)
            qf[kk] = *(const f16x8*)(Q + base + kk * 32 + g16 * 8);
    }

    f32x4 of[8];
#pragma unroll
    for (int cf = 0; cf < 8; cf++) of[cf] = (f32x4){0.f, 0.f, 0.f, 0.f};
    float mr[4], lr[4];
#pragma unroll
    for (int r = 0; r < 4; r++) { mr[r] = -3.0e38f; lr[r] = 0.f; }

    const f16* Kb = Kc + (size_t)kvh * LCTX * 128;
    const f16* Vb = Vc + (size_t)kvh * LCTX * 128;
    const int nt = (PASTN + s0 + 64) >> 6;

    // K staging lane map (source-swizzled)
    const int krow = lane >> 4;
    const int kp   = lane & 15;
    // V staging lane map (source permuted for the tr_b16 subtiled layout)
    const int lv = ((lane >> 3) & 3) * 8 + ((lane >> 5) & 1) * 4 + ((lane >> 1) & 3);
    const int vdo = (lane & 1) * 8;

    const uint32_t vs0 = lds_lo(Vs[0]) + lane * 8;
    const uint32_t vs1 = lds_lo(Vs[1]) + lane * 8;

#define STAGE_KV(l0, buf)                                                     \
    {                                                                         \
        _Pragma("unroll")                                                     \
        for (int j = 0; j < 4; j++) {                                         \
            int r7 = ((j & 1) << 2) + krow;                                   \
            int sg = kp ^ r7;                                                 \
            gl_lds16(Kb + (size_t)((l0) + w * 16 + j * 4 + krow) * 128 + sg * 8, \
                     (void*)(Ks[buf] + (w * 16 + j * 4) * 128));              \
        }                                                                     \
        _Pragma("unroll")                                                     \
        for (int q = 0; q < 4; q++) {                                         \
            int idx2 = w * 4 + q;                                             \
            int ks2 = idx2 >> 3, db = idx2 & 7;                               \
            gl_lds16(Vb + (size_t)((l0) + ks2 * 32 + lv) * 128 + db * 16 + vdo, \
                     (void*)(Vs[buf] + ks2 * 4096 + db * 512));               \
        }                                                                     \
    }

    STAGE_KV(0, 0);
    __syncthreads();

    for (int it = 0; it < nt; ++it) {
        const int l0 = it << 6;
        const int cur = it & 1;

        // prefetch next tile into the other buffer (hidden under compute)
        if (it + 1 < nt) STAGE_KV(l0 + 64, cur ^ 1);

        // ---- S = Q K^T ----
        f32x4 sf[4];
#pragma unroll
        for (int ni = 0; ni < 4; ni++) sf[ni] = (f32x4){0.f, 0.f, 0.f, 0.f};
#pragma unroll
        for (int ni = 0; ni < 4; ni++)
#pragma unroll
            for (int kk = 0; kk < 4; kk++) {
                int r = ni * 16 + l16;
                int g = kk * 4 + g16;
                f16x8 bh = *(const f16x8*)&Ks[cur][r * 128 + ((g ^ (r & 7)) << 3)];
                sf[ni] = mfma16(qf[kk], bh, sf[ni]);
            }

        const bool needmask = (l0 + 63 > PASTN + s0);
#pragma unroll
        for (int r = 0; r < 4; r++) {
            int srow = s0 + w * 16 + (g16 << 2) + r;
            if (needmask) {
#pragma unroll
                for (int ni = 0; ni < 4; ni++) {
                    int col = l0 + ni * 16 + l16;
                    if (col > PASTN + srow) sf[ni][r] = -3.0e38f;
                }
            }
            float mx = fmaxf(fmaxf(sf[0][r], sf[1][r]), fmaxf(sf[2][r], sf[3][r]));
            mx = fmaxf(mx, __shfl_xor(mx, 1));
            mx = fmaxf(mx, __shfl_xor(mx, 2));
            mx = fmaxf(mx, __shfl_xor(mx, 4));
            mx = fmaxf(mx, __shfl_xor(mx, 8));
            // defer-max (T13): only rescale when the running max grew by >8
            if (mx > mr[r] + 8.0f) {
                float corr = __expf(mr[r] - mx);
                mr[r] = mx;
                lr[r] *= corr;
#pragma unroll
                for (int cf = 0; cf < 8; cf++) of[cf][r] *= corr;
            }
            float ss = 0.f;
#pragma unroll
            for (int ni = 0; ni < 4; ni++) {
                float p = __expf(sf[ni][r] - mr[r]);
                sf[ni][r] = p;
                ss += p;
            }
            ss += __shfl_xor(ss, 1);
            ss += __shfl_xor(ss, 2);
            ss += __shfl_xor(ss, 4);
            ss += __shfl_xor(ss, 8);
            lr[r] += ss;
        }

        // ---- P -> wave-private LDS (fp16, swizzled) ----
#pragma unroll
        for (int ni = 0; ni < 4; ni++)
#pragma unroll
            for (int r = 0; r < 4; r++) {
                int row = (g16 << 2) + r;
                int col = ni * 16 + l16;
                Pl[w][row * 64 + (((col >> 3) ^ (row & 7)) << 3) + (col & 7)] =
                    (f16)sf[ni][r];
            }

        // ---- O += P @ V  (V^T fragments via ds_read_b64_tr_b16) ----
#pragma unroll
        for (int ks = 0; ks < 2; ks++) {
            int g = ks * 4 + g16;
            f16x8 pa = *(const f16x8*)&Pl[w][l16 * 64 + ((g ^ (l16 & 7)) << 3)];
            uint32_t va = (cur ? vs1 : vs0) + ks * 8192;
            f16x4 t0, t1, t2, t3, t4, t5, t6, t7;
            f16x4 u0, u1, u2, u3, u4, u5, u6, u7;
            TRRD(t0, va, 0);    TRRD(u0, va, 512);
            TRRD(t1, va, 1024); TRRD(u1, va, 1536);
            TRRD(t2, va, 2048); TRRD(u2, va, 2560);
            TRRD(t3, va, 3072); TRRD(u3, va, 3584);
            TRRD(t4, va, 4096); TRRD(u4, va, 4608);
            TRRD(t5, va, 5120); TRRD(u5, va, 5632);
            TRRD(t6, va, 6144); TRRD(u6, va, 6656);
            TRRD(t7, va, 7168); TRRD(u7, va, 7680);
            asm volatile("s_waitcnt lgkmcnt(0)" ::: "memory");
            __builtin_amdgcn_sched_barrier(0);
#define PV_MFMA(cf, lo, hi)                                        \
            {                                                      \
                f16x8 vb;                                          \
                vb[0] = lo[0]; vb[1] = lo[1]; vb[2] = lo[2];       \
                vb[3] = lo[3]; vb[4] = hi[0]; vb[5] = hi[1];       \
                vb[6] = hi[2]; vb[7] = hi[3];                      \
                of[cf] = mfma16(pa, vb, of[cf]);                   \
            }
            PV_MFMA(0, t0, u0) PV_MFMA(1, t1, u1)
            PV_MFMA(2, t2, u2) PV_MFMA(3, t3, u3)
            PV_MFMA(4, t4, u4) PV_MFMA(5, t5, u5)
            PV_MFMA(6, t6, u6) PV_MFMA(7, t7, u7)
#undef PV_MFMA
        }
        __syncthreads();   // waits vmcnt(0) too -> prefetched tile landed
    }

    // ---- normalize + write o (fp16) ----
#pragma unroll
    for (int cf = 0; cf < 8; cf++)
#pragma unroll
        for (int r = 0; r < 4; r++) {
            int srow = s0 + w * 16 + (g16 << 2) + r;
            int d = cf * 16 + l16;
            Og[(size_t)srow * 4096 + (size_t)h * 128 + d] = (f16)(of[cf][r] / lr[r]);
        }
#undef STAGE_KV
}

// ---------------------------------------------------------------------------
// launcher
// ---------------------------------------------------------------------------
extern "C" void kernel_launch(void* const* d_in, const int* in_sizes, int n_in,
                              void* d_out, int out_size, void* d_ws, size_t ws_size,
                              hipStream_t stream)
{
    const float* hidden = (const float*)d_in[0];
    const float* kvp    = (const float*)d_in[1];
    const float* cosp   = (const float*)d_in[7];
    const float* sinp   = (const float*)d_in[8];
    const float* Wq     = (const float*)d_in[9];
    const float* Wk     = (const float*)d_in[10];
    const float* Wv     = (const float*)d_in[11];
    const float* Wo     = (const float*)d_in[12];
    const int*   layer  = (const int*)d_in[13];

    char* ws = (char*)d_ws;
    f16* w16  = (f16*)ws;                   // 50,331,648 B (Wqkv; later reused for Wo)
    f16* h16  = (f16*)(ws + 50331648);      //  8,388,608
    f16* ck   = (f16*)(ws + 58720256);      //  6,291,456
    f16* cv   = (f16*)(ws + 65011712);      //  6,291,456
    f16* obuf = (f16*)(ws + 71303168);      //  8,388,608

    f16* q16  = (f16*)d_out;                      // 8 MB scratch inside d_out
    f16* kraw = (f16*)((char*)d_out + 8388608);   // 2 MB

    // 1) fp32 -> fp16 conversions
    cvt_f32_f16<<<4096,  256, 0, stream>>>(hidden, h16, 1048576);
    cvt_f32_f16<<<16384, 256, 0, stream>>>(Wq, w16, 4194304);
    cvt_f32_f16<<<4096,  256, 0, stream>>>(Wk, w16 + (size_t)4096 * 4096, 1048576);
    cvt_f32_f16<<<4096,  256, 0, stream>>>(Wv, w16 + (size_t)5120 * 4096, 1048576);

    // 2) fused QKV projection
    gemm_f16<0><<<dim3(48, 8), 256, 0, stream>>>(
        h16, w16, nullptr, q16, kraw, cv, 1024, 6144, 4096);

    // 3) Wo conversion (reuses w16)
    cvt_f32_f16<<<16384, 256, 0, stream>>>(Wo, w16, 4194304);

    // 4) RoPE + cache population
    rope_q<<<1024, 256, 0, stream>>>(q16, cosp, sinp);
    rope_k<<<256, 256, 0, stream>>>(kraw, cosp, sinp, ck);
    cache_conv<<<4096, 256, 0, stream>>>(kvp, layer, ck, cv);

    // 5) flash attention (balanced 1-D grid, double-buffered)
    attn_f16<<<dim3(512), 256, 0, stream>>>(q16, ck, cv, obuf);

    // 6) output projection -> d_out fp32
    gemm_f16<1><<<dim3(32, 8), 256, 0, stream>>>(
        obuf, w16, (float*)d_out, nullptr, nullptr, nullptr, 1024, 4096, 4096);
}

// Round 5
// 287.843 us; speedup vs baseline: 2.8415x; 1.1558x over previous
//
#include <hip/hip_runtime.h>
#include <cstdint>
#include <cstddef>

// ---------------------------------------------------------------------------
// L4maAttention, fp16 pipeline:
//   cvt fp32->fp16 (hidden, Wq,Wk,Wv) -> fused QKV GEMM (global_load_lds,
//   swizzled LDS) -> RoPE(q in-place, k->cache) -> cached-KV convert ->
//   flash attention (fp16; swapped QK^T -> lane-local softmax; dbuf staging;
//   V via ds_read_b64_tr_b16; balanced q-tile remap) -> O-proj GEMM -> fp32.
// ---------------------------------------------------------------------------

typedef _Float16 f16;
typedef f16 f16x8 __attribute__((ext_vector_type(8)));
typedef f16 f16x4 __attribute__((ext_vector_type(4)));
typedef float f32x4 __attribute__((ext_vector_type(4)));

#define HIDN 4096
#define LCTX 3072
#define PASTN 2048
// 1/sqrt(128) * log2(e): QK^T computed in log2 domain (exp2-based softmax)
#define QK_SCALE_LOG2 0.12753102734366334f
#define RESC_THR 11.54f   /* defer-max threshold, log2 units (~8 nats) */

__device__ __forceinline__ f32x4 mfma16(f16x8 a, f16x8 b, f32x4 c) {
    return __builtin_amdgcn_mfma_f32_16x16x32_f16(a, b, c, 0, 0, 0);
}

// global -> LDS direct copy, 16B per lane. LDS dest = wave-uniform base +
// lane*16 (linear); per-lane permutation happens on the GLOBAL source address.
__device__ __forceinline__ void gl_lds16(const void* g, void* l) {
    auto gp = (const __attribute__((address_space(1))) unsigned int*)(uintptr_t)g;
    auto lp = (__attribute__((address_space(3))) unsigned int*)(uintptr_t)l;
    __builtin_amdgcn_global_load_lds(gp, lp, 16, 0, 0);
}

__device__ __forceinline__ uint32_t lds_lo(const void* p) {
    return (uint32_t)(uintptr_t)p;
}

// hardware transpose read (4x16 f16 subtile, column-major delivery)
#define TRRD(dst, va, OFF) \
    asm volatile("ds_read_b64_tr_b16 %0, %1 offset:" #OFF : "=v"(dst) : "v"(va))

// ---------------------------------------------------------------------------
// fp32 -> fp16 conversion (vectorized)
// ---------------------------------------------------------------------------
__global__ void cvt_f32_f16(const float* __restrict__ src, f16* __restrict__ dst, int n4)
{
    int i = blockIdx.x * 256 + threadIdx.x;
    if (i >= n4) return;
    f32x4 v = *(const f32x4*)(src + (size_t)i * 4);
    f16x4 h;
#pragma unroll
    for (int j = 0; j < 4; j++) h[j] = (f16)v[j];
    *(f16x4*)(dst + (size_t)i * 4) = h;
}

// ---------------------------------------------------------------------------
// GEMM: C[M,N] = A[M,K] @ B[N,K]^T, both fp16 row-major. (m97-style)
// ---------------------------------------------------------------------------
template <int EPI>
__global__ __launch_bounds__(256, 3) void gemm_f16(
    const f16* __restrict__ A, const f16* __restrict__ B,
    float* __restrict__ Cf, f16* __restrict__ Cq, f16* __restrict__ Ck,
    f16* __restrict__ Cv, int M, int N, int K)
{
    __shared__ f16 As[128 * 64];
    __shared__ f16 Bs[128 * 64];

    const int t = threadIdx.x, lane = t & 63, w = t >> 6;
    const int wm = w >> 1, wn = w & 1;
    const int l16 = lane & 15, g16 = lane >> 4;
    const int m0 = blockIdx.y * 128, n0 = blockIdx.x * 128;

    const int srow = lane >> 3;
    const int sgr  = (lane & 7) ^ srow;

    const size_t aoff = (size_t)(m0 + w * 32 + srow) * K + sgr * 8;
    const size_t boff = (size_t)(n0 + w * 32 + srow) * K + sgr * 8;

    f32x4 acc[4][4];
#pragma unroll
    for (int i = 0; i < 4; i++)
#pragma unroll
        for (int j = 0; j < 4; j++) acc[i][j] = (f32x4){0.f, 0.f, 0.f, 0.f};

    for (int k0 = 0; k0 < K; k0 += 64) {
#pragma unroll
        for (int j = 0; j < 4; j++) {
            gl_lds16(A + aoff + (size_t)j * 8 * K + k0, (void*)(As + (w * 32 + j * 8) * 64));
            gl_lds16(B + boff + (size_t)j * 8 * K + k0, (void*)(Bs + (w * 32 + j * 8) * 64));
        }
        __syncthreads();

#pragma unroll
        for (int ks = 0; ks < 2; ks++) {
            f16x8 af[4], bfr[4];
#pragma unroll
            for (int mi = 0; mi < 4; mi++) {
                int r = wm * 64 + mi * 16 + l16;
                int g = ks * 4 + g16;
                af[mi] = *(const f16x8*)&As[r * 64 + ((g ^ (r & 7)) << 3)];
            }
#pragma unroll
            for (int ni = 0; ni < 4; ni++) {
                int r = wn * 64 + ni * 16 + l16;
                int g = ks * 4 + g16;
                bfr[ni] = *(const f16x8*)&Bs[r * 64 + ((g ^ (r & 7)) << 3)];
            }
#pragma unroll
            for (int ni = 0; ni < 4; ni++)
#pragma unroll
                for (int mi = 0; mi < 4; mi++)
                    acc[mi][ni] = mfma16(af[mi], bfr[ni], acc[mi][ni]);
        }
        __syncthreads();
    }

#pragma unroll
    for (int mi = 0; mi < 4; mi++)
#pragma unroll
        for (int ni = 0; ni < 4; ni++)
#pragma unroll
            for (int r = 0; r < 4; r++) {
                int row = m0 + wm * 64 + mi * 16 + (g16 << 2) + r;
                int col = n0 + wn * 64 + ni * 16 + l16;
                float val = acc[mi][ni][r];
                if (EPI == 0) {
                    if (col < 4096) {
                        Cq[(size_t)row * 4096 + col] = (f16)val;
                    } else if (col < 5120) {
                        Ck[(size_t)row * 1024 + (col - 4096)] = (f16)val;
                    } else {
                        int c = col - 5120;
                        int hh = c >> 7, d = c & 127;
                        Cv[((size_t)hh * LCTX + PASTN + row) * 128 + d] = (f16)val;
                    }
                } else {
                    Cf[(size_t)row * N + col] = val;
                }
            }
}

// ---------------------------------------------------------------------------
// RoPE q (in place, scale*log2e folded), RoPE k -> cache, cached-KV convert
// ---------------------------------------------------------------------------
__global__ void rope_q(f16* __restrict__ q, const float* __restrict__ cosp,
                       const float* __restrict__ sinp)
{
    int i = blockIdx.x * 256 + threadIdx.x;
    int gd = i & 7, hh = (i >> 3) & 31, s = i >> 8;
    size_t b1 = (size_t)s * 4096 + hh * 128 + gd * 8;
    f16x8 x1 = *(f16x8*)(q + b1);
    f16x8 x2 = *(f16x8*)(q + b1 + 64);
    const float* c1 = cosp + s * 128 + gd * 8;
    const float* s1 = sinp + s * 128 + gd * 8;
    const float* c2 = c1 + 64;
    const float* s2 = s1 + 64;
    f16x8 o1, o2;
#pragma unroll
    for (int j = 0; j < 8; j++) {
        float a = (float)x1[j], b = (float)x2[j];
        o1[j] = (f16)((a * c1[j] - b * s1[j]) * QK_SCALE_LOG2);
        o2[j] = (f16)((b * c2[j] + a * s2[j]) * QK_SCALE_LOG2);
    }
    *(f16x8*)(q + b1) = o1;
    *(f16x8*)(q + b1 + 64) = o2;
}

__global__ void rope_k(const f16* __restrict__ kraw, const float* __restrict__ cosp,
                       const float* __restrict__ sinp, f16* __restrict__ ck)
{
    int i = blockIdx.x * 256 + threadIdx.x;
    int gd = i & 7, kvh = (i >> 3) & 7, s = i >> 6;
    size_t b1 = (size_t)s * 1024 + kvh * 128 + gd * 8;
    f16x8 x1 = *(const f16x8*)(kraw + b1);
    f16x8 x2 = *(const f16x8*)(kraw + b1 + 64);
    const float* c1 = cosp + s * 128 + gd * 8;
    const float* s1 = sinp + s * 128 + gd * 8;
    const float* c2 = c1 + 64;
    const float* s2 = s1 + 64;
    f16x8 o1, o2;
#pragma unroll
    for (int j = 0; j < 8; j++) {
        float a = (float)x1[j], b = (float)x2[j];
        o1[j] = (f16)(a * c1[j] - b * s1[j]);
        o2[j] = (f16)(b * c2[j] + a * s2[j]);
    }
    size_t dst = ((size_t)kvh * LCTX + PASTN + s) * 128 + gd * 8;
    *(f16x8*)(ck + dst) = o1;
    *(f16x8*)(ck + dst + 64) = o2;
}

__global__ void cache_conv(const float* __restrict__ kvp, const int* __restrict__ layer,
                           f16* __restrict__ ck, f16* __restrict__ cv)
{
    int i4 = blockIdx.x * 256 + threadIdx.x;
    int half = i4 >> 19;
    int e = (i4 & 524287) * 4;
    int hh = e >> 18, rem = e & 262143, l = rem >> 7, d = rem & 127;
    int blk = l >> 4, rr = l & 15;
    size_t src = (((size_t)(layer[0] * 2 + half) * 256 + blk) * 8 + hh) * 2048
               + (size_t)rr * 128 + d;
    f32x4 x = *(const f32x4*)(kvp + src);
    f16x4 h;
#pragma unroll
    for (int j = 0; j < 4; j++) h[j] = (f16)x[j];
    size_t dst = ((size_t)hh * LCTX + l) * 128 + d;
    *(f16x4*)((half ? cv : ck) + dst) = h;
}

// ---------------------------------------------------------------------------
// Flash attention, 2-phase double-buffered, swapped QK^T.
// Grid: 512 blocks 1-D; balanced causal remap (b and b+256 sum to 81 tiles).
// Swapped QK^T: sf = mfma(K_frag, Q_frag) -> D[kv=(g16*4+r)][q=l16]: each
// lane owns ONE q-row's scores -> kv-reduce is thread-local + 2 shfl_xor.
// Softmax in log2 domain (scale*log2e folded into q); defer-max (T13).
// ---------------------------------------------------------------------------
__global__ __launch_bounds__(256, 2) void attn_f16(
    const f16* __restrict__ Q, const f16* __restrict__ Kc,
    const f16* __restrict__ Vc, f16* __restrict__ Og)
{
    const int b = blockIdx.x;
    const int idx = b & 255;
    const int h = idx & 31;
    const int jt = idx >> 5;
    const int tile = (b >> 8) ? (15 - jt) : jt;
    const int s0 = tile * 64;
    const int kvh = h >> 2;
    const int t = threadIdx.x, lane = t & 63, w = t >> 6;
    const int l16 = lane & 15, g16 = lane >> 4;

    __shared__ f16 Ks[2][64 * 128];
    __shared__ f16 Vs[2][64 * 128];   // tr_b16-subtiled layout
    __shared__ f16 Pl[4][16 * 64];

    // Q fragments (B-operand of swapped QK^T); rows = s0 + w*16 + l16
    f16x8 qf[4];
    {
        size_t base = (size_t)(s0 + w * 16 + l16) * 4096 + h * 128;
#pragma unroll
        for (int kk = 0; kk < 4; kk++)
            qf[kk] = *(const f16x8*)(Q + base + kk * 32 + g16 * 8);
    }

    f32x4 of[8];
#pragma unroll
    for (int cf = 0; cf < 8; cf++) of[cf] = (f32x4){0.f, 0.f, 0.f, 0.f};
    float mr = -3.0e38f, lr = 0.f;    // per-lane: this lane's q-row (l16)

    const f16* Kb = Kc + (size_t)kvh * LCTX * 128;
    const f16* Vb = Vc + (size_t)kvh * LCTX * 128;
    const int nt = (PASTN + s0 + 64) >> 6;

    // K staging lane map (source-swizzled)
    const int krow = lane >> 4;
    const int kp   = lane & 15;
    // V staging lane map (source permuted for the tr_b16 subtiled layout)
    const int lv = ((lane >> 3) & 3) * 8 + ((lane >> 5) & 1) * 4 + ((lane >> 1) & 3);
    const int vdo = (lane & 1) * 8;

    const uint32_t vs0 = lds_lo(Vs[0]) + lane * 8;
    const uint32_t vs1 = lds_lo(Vs[1]) + lane * 8;

#define STAGE_KV(l0, buf)                                                     \
    {                                                                         \
        _Pragma("unroll")                                                     \
        for (int j = 0; j < 4; j++) {                                         \
            int r7 = ((j & 1) << 2) + krow;                                   \
            int sg = kp ^ r7;                                                 \
            gl_lds16(Kb + (size_t)((l0) + w * 16 + j * 4 + krow) * 128 + sg * 8, \
                     (void*)(Ks[buf] + (w * 16 + j * 4) * 128));              \
        }                                                                     \
        _Pragma("unroll")                                                     \
        for (int q = 0; q < 4; q++) {                                         \
            int idx2 = w * 4 + q;                                             \
            int ks2 = idx2 >> 3, db = idx2 & 7;                               \
            gl_lds16(Vb + (size_t)((l0) + ks2 * 32 + lv) * 128 + db * 16 + vdo, \
                     (void*)(Vs[buf] + ks2 * 4096 + db * 512));               \
        }                                                                     \
    }

    STAGE_KV(0, 0);
    __syncthreads();

    for (int it = 0; it < nt; ++it) {
        const int l0 = it << 6;
        const int cur = it & 1;

        // prefetch next tile into the other buffer (hidden under compute)
        if (it + 1 < nt) STAGE_KV(l0 + 64, cur ^ 1);

        // ---- S^T = K Q^T  (D[kv=(g16<<2)+r][q=l16]) ----
        f32x4 sf[4];
#pragma unroll
        for (int ni = 0; ni < 4; ni++) sf[ni] = (f32x4){0.f, 0.f, 0.f, 0.f};
        __builtin_amdgcn_s_setprio(1);
#pragma unroll
        for (int ni = 0; ni < 4; ni++)
#pragma unroll
            for (int kk = 0; kk < 4; kk++) {
                int r = ni * 16 + l16;
                int g = kk * 4 + g16;
                f16x8 kh = *(const f16x8*)&Ks[cur][r * 128 + ((g ^ (r & 7)) << 3)];
                sf[ni] = mfma16(kh, qf[kk], sf[ni]);
            }
        __builtin_amdgcn_s_setprio(0);

        const int qrow = s0 + w * 16 + l16;       // this lane's q-row
        const bool needmask = (l0 + 63 > PASTN + s0);
        if (needmask) {
#pragma unroll
            for (int ni = 0; ni < 4; ni++)
#pragma unroll
                for (int r = 0; r < 4; r++) {
                    int col = l0 + ni * 16 + (g16 << 2) + r;
                    if (col > PASTN + qrow) sf[ni][r] = -3.0e38f;
                }
        }

        // ---- lane-local softmax (log2 domain) ----
        float mx;
        {
            f32x4 m4 = sf[0];
#pragma unroll
            for (int ni = 1; ni < 4; ni++) {
                m4[0] = fmaxf(m4[0], sf[ni][0]); m4[1] = fmaxf(m4[1], sf[ni][1]);
                m4[2] = fmaxf(m4[2], sf[ni][2]); m4[3] = fmaxf(m4[3], sf[ni][3]);
            }
            mx = fmaxf(fmaxf(m4[0], m4[1]), fmaxf(m4[2], m4[3]));
        }
        mx = fmaxf(mx, __shfl_xor(mx, 16));
        mx = fmaxf(mx, __shfl_xor(mx, 32));
        if (__any(mx > mr + RESC_THR)) {
            float mnew = fmaxf(mr, mx);
            float corr = exp2f(mr - mnew);
            mr = mnew;
            lr *= corr;
            float cr[4];
#pragma unroll
            for (int r = 0; r < 4; r++) cr[r] = __shfl(corr, (g16 << 2) + r);
#pragma unroll
            for (int cf = 0; cf < 8; cf++)
#pragma unroll
                for (int r = 0; r < 4; r++) of[cf][r] *= cr[r];
        }
        float ss = 0.f;
#pragma unroll
        for (int ni = 0; ni < 4; ni++)
#pragma unroll
            for (int r = 0; r < 4; r++) {
                float p = exp2f(sf[ni][r] - mr);
                sf[ni][r] = p;
                ss += p;
            }
        ss += __shfl_xor(ss, 16);
        ss += __shfl_xor(ss, 32);
        lr += ss;

        // ---- P -> wave-private LDS (fp16, packed 8B writes, swizzled) ----
#pragma unroll
        for (int ni = 0; ni < 4; ni++) {
            f16x4 pv;
#pragma unroll
            for (int r = 0; r < 4; r++) pv[r] = (f16)sf[ni][r];
            int off = l16 * 128 + ((((ni << 1) | (g16 >> 1)) ^ (l16 & 7)) << 4)
                    + ((g16 & 1) << 3);
            *(f16x4*)((char*)&Pl[w][0] + off) = pv;
        }

        // ---- O += P @ V  (V^T fragments via ds_read_b64_tr_b16) ----
#pragma unroll
        for (int ks = 0; ks < 2; ks++) {
            int g = ks * 4 + g16;
            f16x8 pa = *(const f16x8*)&Pl[w][l16 * 64 + ((g ^ (l16 & 7)) << 3)];
            uint32_t va = (cur ? vs1 : vs0) + ks * 8192;
            f16x4 t0, t1, t2, t3, t4, t5, t6, t7;
            f16x4 u0, u1, u2, u3, u4, u5, u6, u7;
            TRRD(t0, va, 0);    TRRD(u0, va, 512);
            TRRD(t1, va, 1024); TRRD(u1, va, 1536);
            TRRD(t2, va, 2048); TRRD(u2, va, 2560);
            TRRD(t3, va, 3072); TRRD(u3, va, 3584);
            TRRD(t4, va, 4096); TRRD(u4, va, 4608);
            TRRD(t5, va, 5120); TRRD(u5, va, 5632);
            TRRD(t6, va, 6144); TRRD(u6, va, 6656);
            TRRD(t7, va, 7168); TRRD(u7, va, 7680);
            asm volatile("s_waitcnt lgkmcnt(0)" ::: "memory");
            __builtin_amdgcn_sched_barrier(0);
            __builtin_amdgcn_s_setprio(1);
#define PV_MFMA(cf, lo, hi)                                        \
            {                                                      \
                f16x8 vb;                                          \
                vb[0] = lo[0]; vb[1] = lo[1]; vb[2] = lo[2];       \
                vb[3] = lo[3]; vb[4] = hi[0]; vb[5] = hi[1];       \
                vb[6] = hi[2]; vb[7] = hi[3];                      \
                of[cf] = mfma16(pa, vb, of[cf]);                   \
            }
            PV_MFMA(0, t0, u0) PV_MFMA(1, t1, u1)
            PV_MFMA(2, t2, u2) PV_MFMA(3, t3, u3)
            PV_MFMA(4, t4, u4) PV_MFMA(5, t5, u5)
            PV_MFMA(6, t6, u6) PV_MFMA(7, t7, u7)
#undef PV_MFMA
            __builtin_amdgcn_s_setprio(0);
        }
        __syncthreads();   // waits vmcnt(0) too -> prefetched tile landed
    }

    // ---- normalize + write o (fp16) ----
    float lrr[4];
#pragma unroll
    for (int r = 0; r < 4; r++) lrr[r] = __shfl(lr, (g16 << 2) + r);
#pragma unroll
    for (int cf = 0; cf < 8; cf++)
#pragma unroll
        for (int r = 0; r < 4; r++) {
            int srow = s0 + w * 16 + (g16 << 2) + r;
            int d = cf * 16 + l16;
            Og[(size_t)srow * 4096 + (size_t)h * 128 + d] = (f16)(of[cf][r] / lrr[r]);
        }
#undef STAGE_KV
}

// ---------------------------------------------------------------------------
// launcher
// ---------------------------------------------------------------------------
extern "C" void kernel_launch(void* const* d_in, const int* in_sizes, int n_in,
                              void* d_out, int out_size, void* d_ws, size_t ws_size,
                              hipStream_t stream)
{
    const float* hidden = (const float*)d_in[0];
    const float* kvp    = (const float*)d_in[1];
    const float* cosp   = (const float*)d_in[7];
    const float* sinp   = (const float*)d_in[8];
    const float* Wq     = (const float*)d_in[9];
    const float* Wk     = (const float*)d_in[10];
    const float* Wv     = (const float*)d_in[11];
    const float* Wo     = (const float*)d_in[12];
    const int*   layer  = (const int*)d_in[13];

    char* ws = (char*)d_ws;
    f16* w16  = (f16*)ws;                   // 50,331,648 B (Wqkv; later reused for Wo)
    f16* h16  = (f16*)(ws + 50331648);      //  8,388,608
    f16* ck   = (f16*)(ws + 58720256);      //  6,291,456
    f16* cv   = (f16*)(ws + 65011712);      //  6,291,456
    f16* obuf = (f16*)(ws + 71303168);      //  8,388,608

    f16* q16  = (f16*)d_out;                      // 8 MB scratch inside d_out
    f16* kraw = (f16*)((char*)d_out + 8388608);   // 2 MB

    // 1) fp32 -> fp16 conversions
    cvt_f32_f16<<<4096,  256, 0, stream>>>(hidden, h16, 1048576);
    cvt_f32_f16<<<16384, 256, 0, stream>>>(Wq, w16, 4194304);
    cvt_f32_f16<<<4096,  256, 0, stream>>>(Wk, w16 + (size_t)4096 * 4096, 1048576);
    cvt_f32_f16<<<4096,  256, 0, stream>>>(Wv, w16 + (size_t)5120 * 4096, 1048576);

    // 2) fused QKV projection
    gemm_f16<0><<<dim3(48, 8), 256, 0, stream>>>(
        h16, w16, nullptr, q16, kraw, cv, 1024, 6144, 4096);

    // 3) Wo conversion (reuses w16)
    cvt_f32_f16<<<16384, 256, 0, stream>>>(Wo, w16, 4194304);

    // 4) RoPE + cache population
    rope_q<<<1024, 256, 0, stream>>>(q16, cosp, sinp);
    rope_k<<<256, 256, 0, stream>>>(kraw, cosp, sinp, ck);
    cache_conv<<<4096, 256, 0, stream>>>(kvp, layer, ck, cv);

    // 5) flash attention (balanced 1-D grid, double-buffered, swapped QK^T)
    attn_f16<<<dim3(512), 256, 0, stream>>>(q16, ck, cv, obuf);

    // 6) output projection -> d_out fp32
    gemm_f16<1><<<dim3(32, 8), 256, 0, stream>>>(
        obuf, w16, (float*)d_out, nullptr, nullptr, nullptr, 1024, 4096, 4096);
}

// Round 6
// 277.617 us; speedup vs baseline: 2.9462x; 1.0368x over previous
//
#include <hip/hip_runtime.h>
#include <cstdint>
#include <cstddef>

// ---------------------------------------------------------------------------
// L4maAttention, fp16 pipeline:
//   cvt fp32->fp16 (hidden+Wq+Wk+Wv fused) -> fused QKV GEMM (global_load_lds,
//   swizzled LDS) -> RoPE(q in-place, k->cache) -> cached-KV convert ->
//   flash attention (swapped QK^T lane-local softmax; PV via x16 MFMA fed
//   directly by ds_read_b64_tr_b16, no P-LDS round-trip; dbuf staging;
//   balanced q-tile remap) -> O-proj GEMM -> d_out fp32.
// ---------------------------------------------------------------------------

typedef _Float16 f16;
typedef f16 f16x8 __attribute__((ext_vector_type(8)));
typedef f16 f16x4 __attribute__((ext_vector_type(4)));
typedef float f32x4 __attribute__((ext_vector_type(4)));

#define HIDN 4096
#define LCTX 3072
#define PASTN 2048
// 1/sqrt(128) * log2(e): QK^T computed in log2 domain (exp2-based softmax)
#define QK_SCALE_LOG2 0.12753102734366334f
#define RESC_THR 11.54f   /* defer-max threshold, log2 units (~8 nats) */

__device__ __forceinline__ f32x4 mfma16(f16x8 a, f16x8 b, f32x4 c) {
    return __builtin_amdgcn_mfma_f32_16x16x32_f16(a, b, c, 0, 0, 0);
}
__device__ __forceinline__ f32x4 mfma16k16(f16x4 a, f16x4 b, f32x4 c) {
    return __builtin_amdgcn_mfma_f32_16x16x16f16(a, b, c, 0, 0, 0);
}

// global -> LDS direct copy, 16B per lane. LDS dest = wave-uniform base +
// lane*16 (linear); per-lane permutation happens on the GLOBAL source address.
__device__ __forceinline__ void gl_lds16(const void* g, void* l) {
    auto gp = (const __attribute__((address_space(1))) unsigned int*)(uintptr_t)g;
    auto lp = (__attribute__((address_space(3))) unsigned int*)(uintptr_t)l;
    __builtin_amdgcn_global_load_lds(gp, lp, 16, 0, 0);
}

__device__ __forceinline__ uint32_t lds_lo(const void* p) {
    return (uint32_t)(uintptr_t)p;
}

// hardware transpose read (4x16 f16 subtile, column-major delivery)
#define TRRD(dst, va, OFF) \
    asm volatile("ds_read_b64_tr_b16 %0, %1 offset:" #OFF : "=v"(dst) : "v"(va))
#define WAITL(N) \
    asm volatile("s_waitcnt lgkmcnt(" #N ")" ::: "memory"); \
    __builtin_amdgcn_sched_barrier(0)

// ---------------------------------------------------------------------------
// fused fp32 -> fp16 conversions: hidden (1M x4), Wq (4M x4), Wk (1M x4),
// Wv (1M x4); grid = 28672 x 256 covers 7,340,032 float4s exactly.
// ---------------------------------------------------------------------------
__global__ void cvt_all(const float* __restrict__ hidden, const float* __restrict__ Wq,
                        const float* __restrict__ Wk, const float* __restrict__ Wv,
                        f16* __restrict__ h16, f16* __restrict__ w16)
{
    int i = blockIdx.x * 256 + threadIdx.x;
    const float* src; f16* dst; int off;
    if (i < 1048576)      { src = hidden; dst = h16; off = i; }
    else if (i < 5242880) { src = Wq; dst = w16; off = i - 1048576; }
    else if (i < 6291456) { src = Wk; dst = w16 + (size_t)4096 * 4096; off = i - 5242880; }
    else                  { src = Wv; dst = w16 + (size_t)5120 * 4096; off = i - 6291456; }
    f32x4 v = *(const f32x4*)(src + (size_t)off * 4);
    f16x4 h;
#pragma unroll
    for (int j = 0; j < 4; j++) h[j] = (f16)v[j];
    *(f16x4*)(dst + (size_t)off * 4) = h;
}

__global__ void cvt_f32_f16(const float* __restrict__ src, f16* __restrict__ dst, int n4)
{
    int i = blockIdx.x * 256 + threadIdx.x;
    if (i >= n4) return;
    f32x4 v = *(const f32x4*)(src + (size_t)i * 4);
    f16x4 h;
#pragma unroll
    for (int j = 0; j < 4; j++) h[j] = (f16)v[j];
    *(f16x4*)(dst + (size_t)i * 4) = h;
}

// ---------------------------------------------------------------------------
// GEMM: C[M,N] = A[M,K] @ B[N,K]^T, both fp16 row-major. (m97-style)
// ---------------------------------------------------------------------------
template <int EPI>
__global__ __launch_bounds__(256, 3) void gemm_f16(
    const f16* __restrict__ A, const f16* __restrict__ B,
    float* __restrict__ Cf, f16* __restrict__ Cq, f16* __restrict__ Ck,
    f16* __restrict__ Cv, int M, int N, int K)
{
    __shared__ f16 As[128 * 64];
    __shared__ f16 Bs[128 * 64];

    const int t = threadIdx.x, lane = t & 63, w = t >> 6;
    const int wm = w >> 1, wn = w & 1;
    const int l16 = lane & 15, g16 = lane >> 4;
    const int m0 = blockIdx.y * 128, n0 = blockIdx.x * 128;

    const int srow = lane >> 3;
    const int sgr  = (lane & 7) ^ srow;

    const size_t aoff = (size_t)(m0 + w * 32 + srow) * K + sgr * 8;
    const size_t boff = (size_t)(n0 + w * 32 + srow) * K + sgr * 8;

    f32x4 acc[4][4];
#pragma unroll
    for (int i = 0; i < 4; i++)
#pragma unroll
        for (int j = 0; j < 4; j++) acc[i][j] = (f32x4){0.f, 0.f, 0.f, 0.f};

    for (int k0 = 0; k0 < K; k0 += 64) {
#pragma unroll
        for (int j = 0; j < 4; j++) {
            gl_lds16(A + aoff + (size_t)j * 8 * K + k0, (void*)(As + (w * 32 + j * 8) * 64));
            gl_lds16(B + boff + (size_t)j * 8 * K + k0, (void*)(Bs + (w * 32 + j * 8) * 64));
        }
        __syncthreads();

#pragma unroll
        for (int ks = 0; ks < 2; ks++) {
            f16x8 af[4], bfr[4];
#pragma unroll
            for (int mi = 0; mi < 4; mi++) {
                int r = wm * 64 + mi * 16 + l16;
                int g = ks * 4 + g16;
                af[mi] = *(const f16x8*)&As[r * 64 + ((g ^ (r & 7)) << 3)];
            }
#pragma unroll
            for (int ni = 0; ni < 4; ni++) {
                int r = wn * 64 + ni * 16 + l16;
                int g = ks * 4 + g16;
                bfr[ni] = *(const f16x8*)&Bs[r * 64 + ((g ^ (r & 7)) << 3)];
            }
#pragma unroll
            for (int ni = 0; ni < 4; ni++)
#pragma unroll
                for (int mi = 0; mi < 4; mi++)
                    acc[mi][ni] = mfma16(af[mi], bfr[ni], acc[mi][ni]);
        }
        __syncthreads();
    }

#pragma unroll
    for (int mi = 0; mi < 4; mi++)
#pragma unroll
        for (int ni = 0; ni < 4; ni++)
#pragma unroll
            for (int r = 0; r < 4; r++) {
                int row = m0 + wm * 64 + mi * 16 + (g16 << 2) + r;
                int col = n0 + wn * 64 + ni * 16 + l16;
                float val = acc[mi][ni][r];
                if (EPI == 0) {
                    if (col < 4096) {
                        Cq[(size_t)row * 4096 + col] = (f16)val;
                    } else if (col < 5120) {
                        Ck[(size_t)row * 1024 + (col - 4096)] = (f16)val;
                    } else {
                        int c = col - 5120;
                        int hh = c >> 7, d = c & 127;
                        Cv[((size_t)hh * LCTX + PASTN + row) * 128 + d] = (f16)val;
                    }
                } else {
                    Cf[(size_t)row * N + col] = val;
                }
            }
}

// ---------------------------------------------------------------------------
// RoPE q (in place, scale*log2e folded), RoPE k -> cache, cached-KV convert
// ---------------------------------------------------------------------------
__global__ void rope_q(f16* __restrict__ q, const float* __restrict__ cosp,
                       const float* __restrict__ sinp)
{
    int i = blockIdx.x * 256 + threadIdx.x;
    int gd = i & 7, hh = (i >> 3) & 31, s = i >> 8;
    size_t b1 = (size_t)s * 4096 + hh * 128 + gd * 8;
    f16x8 x1 = *(f16x8*)(q + b1);
    f16x8 x2 = *(f16x8*)(q + b1 + 64);
    const float* c1 = cosp + s * 128 + gd * 8;
    const float* s1 = sinp + s * 128 + gd * 8;
    const float* c2 = c1 + 64;
    const float* s2 = s1 + 64;
    f16x8 o1, o2;
#pragma unroll
    for (int j = 0; j < 8; j++) {
        float a = (float)x1[j], b = (float)x2[j];
        o1[j] = (f16)((a * c1[j] - b * s1[j]) * QK_SCALE_LOG2);
        o2[j] = (f16)((b * c2[j] + a * s2[j]) * QK_SCALE_LOG2);
    }
    *(f16x8*)(q + b1) = o1;
    *(f16x8*)(q + b1 + 64) = o2;
}

__global__ void rope_k(const f16* __restrict__ kraw, const float* __restrict__ cosp,
                       const float* __restrict__ sinp, f16* __restrict__ ck)
{
    int i = blockIdx.x * 256 + threadIdx.x;
    int gd = i & 7, kvh = (i >> 3) & 7, s = i >> 6;
    size_t b1 = (size_t)s * 1024 + kvh * 128 + gd * 8;
    f16x8 x1 = *(const f16x8*)(kraw + b1);
    f16x8 x2 = *(const f16x8*)(kraw + b1 + 64);
    const float* c1 = cosp + s * 128 + gd * 8;
    const float* s1 = sinp + s * 128 + gd * 8;
    const float* c2 = c1 + 64;
    const float* s2 = s1 + 64;
    f16x8 o1, o2;
#pragma unroll
    for (int j = 0; j < 8; j++) {
        float a = (float)x1[j], b = (float)x2[j];
        o1[j] = (f16)(a * c1[j] - b * s1[j]);
        o2[j] = (f16)(b * c2[j] + a * s2[j]);
    }
    size_t dst = ((size_t)kvh * LCTX + PASTN + s) * 128 + gd * 8;
    *(f16x8*)(ck + dst) = o1;
    *(f16x8*)(ck + dst + 64) = o2;
}

__global__ void cache_conv(const float* __restrict__ kvp, const int* __restrict__ layer,
                           f16* __restrict__ ck, f16* __restrict__ cv)
{
    int i4 = blockIdx.x * 256 + threadIdx.x;
    int half = i4 >> 19;
    int e = (i4 & 524287) * 4;
    int hh = e >> 18, rem = e & 262143, l = rem >> 7, d = rem & 127;
    int blk = l >> 4, rr = l & 15;
    size_t src = (((size_t)(layer[0] * 2 + half) * 256 + blk) * 8 + hh) * 2048
               + (size_t)rr * 128 + d;
    f32x4 x = *(const f32x4*)(kvp + src);
    f16x4 h;
#pragma unroll
    for (int j = 0; j < 4; j++) h[j] = (f16)x[j];
    size_t dst = ((size_t)hh * LCTX + l) * 128 + d;
    *(f16x4*)((half ? cv : ck) + dst) = h;
}

// ---------------------------------------------------------------------------
// Flash attention, 2-phase double-buffered, swapped QK^T, x16-MFMA PV.
// Grid: 512 blocks 1-D; balanced causal remap (b and b+256 sum to 81 tiles).
// Swapped QK^T (x32): sf[ni][r] = S[kv=ni*16+4*g16+r][q=l16].
// PV: V staged into region layout R=cf*16+ni*4+g16 (64 f16 regions holding
// V[l0+ni*16+4g16+j][cf*16+p]); ds_read_b64_tr_b16 at offset 512*(4cf+ni)
// delivers exactly the 16x16x16 B-frag; pa[ni]=(f16x4)sf[ni] is the A-frag.
// No P-LDS round-trip, no repack movs. Counted-lgkmcnt read pipeline.
// ---------------------------------------------------------------------------
__global__ __launch_bounds__(256, 2) void attn_f16(
    const f16* __restrict__ Q, const f16* __restrict__ Kc,
    const f16* __restrict__ Vc, f16* __restrict__ Og)
{
    const int b = blockIdx.x;
    const int idx = b & 255;
    const int h = idx & 31;
    const int jt = idx >> 5;
    const int tile = (b >> 8) ? (15 - jt) : jt;
    const int s0 = tile * 64;
    const int kvh = h >> 2;
    const int t = threadIdx.x, lane = t & 63, w = t >> 6;
    const int l16 = lane & 15, g16 = lane >> 4;

    __shared__ f16 Ks[2][64 * 128];
    __shared__ f16 Vs[2][64 * 128];   // x16-tr region layout (see header)

    // Q fragments (B-operand of swapped QK^T); rows = s0 + w*16 + l16
    f16x8 qf[4];
    {
        size_t base = (size_t)(s0 + w * 16 + l16) * 4096 + h * 128;
#pragma unroll
        for (int kk = 0; kk < 4; kk++)
            qf[kk] = *(const f16x8*)(Q + base + kk * 32 + g16 * 8);
    }

    f32x4 of[8];
#pragma unroll
    for (int cf = 0; cf < 8; cf++) of[cf] = (f32x4){0.f, 0.f, 0.f, 0.f};
    float mr = -3.0e38f, lr = 0.f;    // per-lane; lr holds a PARTIAL sum

    const f16* Kb = Kc + (size_t)kvh * LCTX * 128;
    const f16* Vb = Vc + (size_t)kvh * LCTX * 128;
    const int nt = (PASTN + s0 + 64) >> 6;

    // K staging lane map (source-swizzled)
    const int krow = lane >> 4;
    const int kp   = lane & 15;
    // V staging lane map for the x16 region layout:
    // load idx=w*4+q covers regions idx*8..idx*8+7; this lane writes
    // V[l0 + (q&1)*32 + vrow][ (w*2+(q>>1))*16 + vch .. +8 ]
    const int vrow = ((lane >> 5) << 4) + (((lane >> 3) & 3) << 2) + ((lane >> 1) & 3);
    const int vch  = (lane & 1) << 3;

    const uint32_t vs0 = lds_lo(Vs[0]) + lane * 8;
    const uint32_t vs1 = lds_lo(Vs[1]) + lane * 8;

#define STAGE_KV(l0, buf)                                                     \
    {                                                                         \
        _Pragma("unroll")                                                     \
        for (int j = 0; j < 4; j++) {                                         \
            int r7 = ((j & 1) << 2) + krow;                                   \
            int sg = kp ^ r7;                                                 \
            gl_lds16(Kb + (size_t)((l0) + w * 16 + j * 4 + krow) * 128 + sg * 8, \
                     (void*)(Ks[buf] + (w * 16 + j * 4) * 128));              \
        }                                                                     \
        _Pragma("unroll")                                                     \
        for (int q = 0; q < 4; q++) {                                         \
            gl_lds16(Vb + (size_t)((l0) + (q & 1) * 32 + vrow) * 128          \
                        + (w * 2 + (q >> 1)) * 16 + vch,                      \
                     (void*)(Vs[buf] + (w * 4 + q) * 512));                   \
        }                                                                     \
    }

    STAGE_KV(0, 0);
    __syncthreads();

    for (int it = 0; it < nt; ++it) {
        const int l0 = it << 6;
        const int cur = it & 1;

        // prefetch next tile into the other buffer (hidden under compute)
        if (it + 1 < nt) STAGE_KV(l0 + 64, cur ^ 1);

        // ---- S^T = K Q^T  (D[kv=(g16<<2)+r + 16ni][q=l16]) ----
        f32x4 sf[4];
#pragma unroll
        for (int ni = 0; ni < 4; ni++) sf[ni] = (f32x4){0.f, 0.f, 0.f, 0.f};
        __builtin_amdgcn_s_setprio(1);
#pragma unroll
        for (int ni = 0; ni < 4; ni++)
#pragma unroll
            for (int kk = 0; kk < 4; kk++) {
                int r = ni * 16 + l16;
                int g = kk * 4 + g16;
                f16x8 kh = *(const f16x8*)&Ks[cur][r * 128 + ((g ^ (r & 7)) << 3)];
                sf[ni] = mfma16(kh, qf[kk], sf[ni]);
            }
        __builtin_amdgcn_s_setprio(0);

        const int qrow = s0 + w * 16 + l16;       // this lane's q-row
        const bool needmask = (l0 + 63 > PASTN + s0);
        if (needmask) {
#pragma unroll
            for (int ni = 0; ni < 4; ni++)
#pragma unroll
                for (int r = 0; r < 4; r++) {
                    int col = l0 + ni * 16 + (g16 << 2) + r;
                    if (col > PASTN + qrow) sf[ni][r] = -3.0e38f;
                }
        }

        // ---- lane-local softmax (log2 domain), deferred sum-reduce ----
        float mx;
        {
            f32x4 m4 = sf[0];
#pragma unroll
            for (int ni = 1; ni < 4; ni++) {
                m4[0] = fmaxf(m4[0], sf[ni][0]); m4[1] = fmaxf(m4[1], sf[ni][1]);
                m4[2] = fmaxf(m4[2], sf[ni][2]); m4[3] = fmaxf(m4[3], sf[ni][3]);
            }
            mx = fmaxf(fmaxf(m4[0], m4[1]), fmaxf(m4[2], m4[3]));
        }
        mx = fmaxf(mx, __shfl_xor(mx, 16));
        mx = fmaxf(mx, __shfl_xor(mx, 32));
        if (__any(mx > mr + RESC_THR)) {
            float mnew = fmaxf(mr, mx);
            float corr = exp2f(mr - mnew);    // row-uniform
            mr = mnew;
            lr *= corr;                       // partial sum scales consistently
            float cr[4];
#pragma unroll
            for (int r = 0; r < 4; r++) cr[r] = __shfl(corr, (g16 << 2) + r);
#pragma unroll
            for (int cf = 0; cf < 8; cf++)
#pragma unroll
                for (int r = 0; r < 4; r++) of[cf][r] *= cr[r];
        }
#pragma unroll
        for (int ni = 0; ni < 4; ni++)
#pragma unroll
            for (int r = 0; r < 4; r++) {
                float p = exp2f(sf[ni][r] - mr);
                sf[ni][r] = p;
                lr += p;                      // lane-partial; reduced after loop
            }

        // ---- P fragments directly from sf (x16 A-frag: k = 4*g16 + r) ----
        f16x4 pa[4];
#pragma unroll
        for (int ni = 0; ni < 4; ni++) {
            pa[ni][0] = (f16)sf[ni][0]; pa[ni][1] = (f16)sf[ni][1];
            pa[ni][2] = (f16)sf[ni][2]; pa[ni][3] = (f16)sf[ni][3];
        }

        // ---- O += P @ V  (32 tr-reads feeding 32 x16 MFMAs, counted waits) --
        {
            const uint32_t va = cur ? vs1 : vs0;
            f16x4 r0,r1,r2,r3,r4,r5,r6,r7,r8,r9,r10,r11,r12,r13,r14,r15,
                  r16,r17,r18,r19,r20,r21,r22,r23,r24,r25,r26,r27,r28,r29,r30,r31;
            __builtin_amdgcn_s_setprio(1);
            TRRD(r0,va,0);      TRRD(r1,va,512);    TRRD(r2,va,1024);   TRRD(r3,va,1536);
            TRRD(r4,va,2048);   TRRD(r5,va,2560);   TRRD(r6,va,3072);   TRRD(r7,va,3584);
            TRRD(r8,va,4096);   TRRD(r9,va,4608);   TRRD(r10,va,5120);  TRRD(r11,va,5632);
#define X16(cf, ni, reg) of[cf] = mfma16k16(pa[ni], reg, of[cf]);
            WAITL(8);
            X16(0,0,r0)  X16(0,1,r1)  X16(0,2,r2)  X16(0,3,r3)
            TRRD(r12,va,6144);  TRRD(r13,va,6656);  TRRD(r14,va,7168);  TRRD(r15,va,7680);
            WAITL(8);
            X16(1,0,r4)  X16(1,1,r5)  X16(1,2,r6)  X16(1,3,r7)
            TRRD(r16,va,8192);  TRRD(r17,va,8704);  TRRD(r18,va,9216);  TRRD(r19,va,9728);
            WAITL(8);
            X16(2,0,r8)  X16(2,1,r9)  X16(2,2,r10) X16(2,3,r11)
            TRRD(r20,va,10240); TRRD(r21,va,10752); TRRD(r22,va,11264); TRRD(r23,va,11776);
            WAITL(8);
            X16(3,0,r12) X16(3,1,r13) X16(3,2,r14) X16(3,3,r15)
            TRRD(r24,va,12288); TRRD(r25,va,12800); TRRD(r26,va,13312); TRRD(r27,va,13824);
            WAITL(8);
            X16(4,0,r16) X16(4,1,r17) X16(4,2,r18) X16(4,3,r19)
            TRRD(r28,va,14336); TRRD(r29,va,14848); TRRD(r30,va,15360); TRRD(r31,va,15872);
            WAITL(8);
            X16(5,0,r20) X16(5,1,r21) X16(5,2,r22) X16(5,3,r23)
            WAITL(4);
            X16(6,0,r24) X16(6,1,r25) X16(6,2,r26) X16(6,3,r27)
            WAITL(0);
            X16(7,0,r28) X16(7,1,r29) X16(7,2,r30) X16(7,3,r31)
#undef X16
            __builtin_amdgcn_s_setprio(0);
        }
        __syncthreads();   // waits vmcnt(0) too -> prefetched tile landed
    }

    // ---- final sum-reduce, normalize + write o (fp16) ----
    lr += __shfl_xor(lr, 16);
    lr += __shfl_xor(lr, 32);
    float lrr[4];
#pragma unroll
    for (int r = 0; r < 4; r++) lrr[r] = __shfl(lr, (g16 << 2) + r);
#pragma unroll
    for (int cf = 0; cf < 8; cf++)
#pragma unroll
        for (int r = 0; r < 4; r++) {
            int srow = s0 + w * 16 + (g16 << 2) + r;
            int d = cf * 16 + l16;
            Og[(size_t)srow * 4096 + (size_t)h * 128 + d] = (f16)(of[cf][r] / lrr[r]);
        }
#undef STAGE_KV
}

// ---------------------------------------------------------------------------
// launcher
// ---------------------------------------------------------------------------
extern "C" void kernel_launch(void* const* d_in, const int* in_sizes, int n_in,
                              void* d_out, int out_size, void* d_ws, size_t ws_size,
                              hipStream_t stream)
{
    const float* hidden = (const float*)d_in[0];
    const float* kvp    = (const float*)d_in[1];
    const float* cosp   = (const float*)d_in[7];
    const float* sinp   = (const float*)d_in[8];
    const float* Wq     = (const float*)d_in[9];
    const float* Wk     = (const float*)d_in[10];
    const float* Wv     = (const float*)d_in[11];
    const float* Wo     = (const float*)d_in[12];
    const int*   layer  = (const int*)d_in[13];

    char* ws = (char*)d_ws;
    f16* w16  = (f16*)ws;                   // 50,331,648 B (Wqkv; later reused for Wo)
    f16* h16  = (f16*)(ws + 50331648);      //  8,388,608
    f16* ck   = (f16*)(ws + 58720256);      //  6,291,456
    f16* cv   = (f16*)(ws + 65011712);      //  6,291,456
    f16* obuf = (f16*)(ws + 71303168);      //  8,388,608

    f16* q16  = (f16*)d_out;                      // 8 MB scratch inside d_out
    f16* kraw = (f16*)((char*)d_out + 8388608);   // 2 MB

    // 1) fp32 -> fp16 conversions (hidden + Wq + Wk + Wv, one launch)
    cvt_all<<<28672, 256, 0, stream>>>(hidden, Wq, Wk, Wv, h16, w16);

    // 2) fused QKV projection
    gemm_f16<0><<<dim3(48, 8), 256, 0, stream>>>(
        h16, w16, nullptr, q16, kraw, cv, 1024, 6144, 4096);

    // 3) Wo conversion (reuses w16)
    cvt_f32_f16<<<16384, 256, 0, stream>>>(Wo, w16, 4194304);

    // 4) RoPE + cache population
    rope_q<<<1024, 256, 0, stream>>>(q16, cosp, sinp);
    rope_k<<<256, 256, 0, stream>>>(kraw, cosp, sinp, ck);
    cache_conv<<<4096, 256, 0, stream>>>(kvp, layer, ck, cv);

    // 5) flash attention (balanced 1-D grid, double-buffered, x16 PV)
    attn_f16<<<dim3(512), 256, 0, stream>>>(q16, ck, cv, obuf);

    // 6) output projection -> d_out fp32
    gemm_f16<1><<<dim3(32, 8), 256, 0, stream>>>(
        obuf, w16, (float*)d_out, nullptr, nullptr, nullptr, 1024, 4096, 4096);
}